// Round 8
// baseline (342.438 us; speedup 1.0000x reference)
//
#include <hip/hip_runtime.h>
#include <hip/hip_bf16.h>

// ModernBertAttention: B=4 S=2048 H=1024 NH=16 HD=64, rope theta=160000, f32 in/out.
// R8: attn = BARRIER-FREE: 1 wave/block, 32 q/wave, K/V fragments streamed
//     global->VGPR (L1/L2-resident; no LDS, no __syncthreads, no lockstep).
//     In-register P relayout (cvt_pk+permlane32_swap). GEMMs/vtrans/cvt unchanged.

#define GLOBAL_AS __attribute__((address_space(1)))
#define LDS_AS    __attribute__((address_space(3)))

using f32x4  = __attribute__((ext_vector_type(4))) float;
using f32x16 = __attribute__((ext_vector_type(16))) float;
using s16x8  = __attribute__((ext_vector_type(8))) short;

__device__ __forceinline__ void gld_lds16(const void* g, void* l) {
  __builtin_amdgcn_global_load_lds((const GLOBAL_AS void*)g, (LDS_AS void*)l, 16, 0, 0);
}

__device__ __forceinline__ unsigned short f2bf(float f) {
  unsigned int u = __float_as_uint(f);
  u = (u + 0x7fffu + ((u >> 16) & 1u)) >> 16;   // RNE
  return (unsigned short)u;
}
__device__ __forceinline__ unsigned int cvt_pk_bf16(float lo, float hi) {
  unsigned int r;
  asm("v_cvt_pk_bf16_f32 %0, %1, %2" : "=v"(r) : "v"(lo), "v"(hi));
  return r;
}
// swap hi32 lanes of a with lo32 lanes of b
__device__ __forceinline__ void pswap(unsigned int& a, unsigned int& b) {
  asm("v_permlane32_swap_b32 %0, %1" : "+v"(a), "+v"(b));
}

// ---------------- merged f32 -> bf16 convert (4 elems/thread) ----------------
__global__ __launch_bounds__(256) void cvt_all_kernel(const float* __restrict__ h,
                                                      const float* __restrict__ wq,
                                                      const float* __restrict__ wo,
                                                      unsigned short* __restrict__ hb,
                                                      unsigned short* __restrict__ wqb,
                                                      unsigned short* __restrict__ wob) {
  int b = blockIdx.x;
  const float* src; unsigned short* dst; int i;
  if (b < 8192)       { src = h;  dst = hb;  i = b * 256 + threadIdx.x; }
  else if (b < 11264) { src = wq; dst = wqb; i = (b - 8192) * 256 + threadIdx.x; }
  else                { src = wo; dst = wob; i = (b - 11264) * 256 + threadIdx.x; }
  float4 v = ((const float4*)src)[i];
  ushort4 o;
  o.x = f2bf(v.x); o.y = f2bf(v.y); o.z = f2bf(v.z); o.w = f2bf(v.w);
  ((ushort4*)dst)[i] = o;
}

// ---------------- rope cos/sin table: idx = (b*2048+s)*32 + d ----------------
__global__ __launch_bounds__(256) void rope_table_kernel(const int* __restrict__ pos,
                                                         float* __restrict__ ctab,
                                                         float* __restrict__ stab) {
  int idx = blockIdx.x * 256 + threadIdx.x;   // B*S*32 total
  int d = idx & 31;
  int bs = idx >> 5;
  float p = (float)pos[bs];
  float inv = exp2f(-(float)d * 0.5402410118609203f);  // theta^(-d/32)
  float f = p * inv;
  ctab[idx] = cosf(f);
  stab[idx] = sinf(f);
}

// ---------------- GEMM C[m,n] = sum_k A[m,k]*B[n,k], bf16 in, 128x128 tile, BK=64 ----------------
// MODE 1: f32 C store. MODE 2: fused QKV epilogue (rope -> Qr/Kr, V -> vbuf).
template<int MODE>
__global__ __launch_bounds__(256) void gemm_bt_kernel(const unsigned short* __restrict__ A,
                                                      const unsigned short* __restrict__ Bm,
                                                      void* __restrict__ C, int N, int K,
                                                      const float* __restrict__ ctab,
                                                      const float* __restrict__ stab,
                                                      unsigned short* __restrict__ Qr,
                                                      unsigned short* __restrict__ Kr,
                                                      unsigned short* __restrict__ vbuf) {
  __shared__ char sA[16384];   // 128 rows x 64 bf16 (128B rows), XOR-swizzled (row&7)<<4
  __shared__ char sB[16384];
  const int tid  = threadIdx.x;
  const int lane = tid & 63, w = tid >> 6;
  const int g = lane >> 4, c = lane & 15;
  const int wr = w >> 1, wc = w & 1;
  const int m0 = blockIdx.x * 128, n0 = blockIdx.y * 128;
  const char* Ab = (const char*)A;
  const char* Bb = (const char*)Bm;

  f32x4 acc[4][4] = {};
  for (int k0 = 0; k0 < K; k0 += 64) {
    __syncthreads();
#pragma unroll
    for (int rr = 0; rr < 4; ++rr) {
      int o = tid * 16 + rr * 4096;
      int row = o >> 7;
      int col = (o & 127) ^ ((row & 7) << 4);   // pre-swizzled source column
      gld_lds16(Ab + ((size_t)(m0 + row) * K + k0) * 2 + col, sA + o);
      gld_lds16(Bb + ((size_t)(n0 + row) * K + k0) * 2 + col, sB + o);
    }
    __syncthreads();
#pragma unroll
    for (int ks = 0; ks < 2; ++ks) {
      s16x8 af[4], bfr[4];
#pragma unroll
      for (int i = 0; i < 4; ++i) {
        int row = 64 * wr + 16 * i + c;
        af[i] = *(const s16x8*)(sA + ((row * 128 + ks * 64 + g * 16) ^ ((row & 7) << 4)));
      }
#pragma unroll
      for (int j = 0; j < 4; ++j) {
        int row = 64 * wc + 16 * j + c;
        bfr[j] = *(const s16x8*)(sB + ((row * 128 + ks * 64 + g * 16) ^ ((row & 7) << 4)));
      }
#pragma unroll
      for (int i = 0; i < 4; ++i)
#pragma unroll
        for (int j = 0; j < 4; ++j)
          acc[i][j] = __builtin_amdgcn_mfma_f32_16x16x32_bf16(af[i], bfr[j], acc[i][j], 0, 0, 0);
    }
  }

  if (MODE == 1) {
#pragma unroll
    for (int i = 0; i < 4; ++i)
#pragma unroll
      for (int j = 0; j < 4; ++j)
#pragma unroll
        for (int r = 0; r < 4; ++r) {
          int m = m0 + 64 * wr + 16 * i + 4 * g + r;
          int n = n0 + 64 * wc + 16 * j + c;
          ((float*)C)[(size_t)m * N + n] = acc[i][j][r];
        }
  } else {
    const int t = blockIdx.y;   // 0..7 Q, 8..15 K, 16..23 V
    if (t < 16) {
      unsigned short* dstb = (t < 8) ? Qr : Kr;
      const float qs = (t < 8) ? 0.18033688011112042f : 1.0f;  // SCALE*log2(e) on Q
      const int h = 2 * (t & 7) + wc;
#pragma unroll
      for (int i = 0; i < 4; ++i)
#pragma unroll
        for (int r = 0; r < 4; ++r) {
          int m = m0 + 64 * wr + 16 * i + 4 * g + r;
          int b = m >> 11, s = m & 2047;
          unsigned short* drow = dstb + ((size_t)(b * 16 + h) * 2048 + s) * 64;
#pragma unroll
          for (int j = 0; j < 2; ++j) {
            int d = 16 * j + c;
            float co = ctab[(size_t)m * 32 + d];
            float si = stab[(size_t)m * 32 + d];
            float x1 = acc[i][j][r], x2 = acc[i][j + 2][r];
            drow[d]      = f2bf((x1 * co - x2 * si) * qs);
            drow[d + 32] = f2bf((x2 * co + x1 * si) * qs);
          }
        }
    } else {
#pragma unroll
      for (int i = 0; i < 4; ++i)
#pragma unroll
        for (int j = 0; j < 4; ++j)
#pragma unroll
          for (int r = 0; r < 4; ++r) {
            int m = m0 + 64 * wr + 16 * i + 4 * g + r;
            int n = (t - 16) * 128 + 64 * wc + 16 * j + c;
            vbuf[(size_t)m * 1024 + n] = f2bf(acc[i][j][r]);
          }
    }
  }
}

// ---------------- V transpose: vbuf (B*S,1024) -> Vt (B,NH,64,S) ----------------
__global__ __launch_bounds__(256) void vtrans_kernel(const unsigned short* __restrict__ vbuf,
                                                     unsigned short* __restrict__ Vt) {
  __shared__ unsigned short tile[64][80];
  int bid = blockIdx.x;                      // b*16*32 + h*32 + st
  int st = bid & 31, h = (bid >> 5) & 15, b = bid >> 9;
  int s0 = st * 64;
  int t = threadIdx.x;
  {
    int row = t >> 2, part = t & 3;
    const unsigned short* src = vbuf + ((size_t)(b * 2048 + s0 + row)) * 1024 + h * 64 + part * 16;
    uint4 v0 = *(const uint4*)(src);
    uint4 v1 = *(const uint4*)(src + 8);
    *(uint4*)&tile[row][part * 16]     = v0;
    *(uint4*)&tile[row][part * 16 + 8] = v1;
  }
  __syncthreads();
  {
    int d = t >> 2, sp = t & 3;
    unsigned short vals[16];
#pragma unroll
    for (int i = 0; i < 16; ++i) vals[i] = tile[sp * 16 + i][d];
    unsigned short* dst = Vt + ((size_t)(b * 16 + h) * 64 + d) * 2048 + s0 + sp * 16;
    *(uint4*)(dst)     = ((const uint4*)vals)[0];
    *(uint4*)(dst + 8) = ((const uint4*)vals)[1];
  }
}

// ---------------- flash attention: barrier-free, 1 wave/block, 32 q/wave ----------------
// Swapped QK^T on 32x32x16 MFMA; K/V A-operand fragments loaded per-lane from global
// (L1/L2-resident tiles); software-pipelined one tile ahead; in-register P relayout;
// fixed m=0 exp2 softmax. No LDS, no barriers.
__global__ __launch_bounds__(64) void attn_kernel(const unsigned short* __restrict__ Q,
                                                  const unsigned short* __restrict__ Kr,
                                                  const unsigned short* __restrict__ Vt,
                                                  unsigned short* __restrict__ Ctx) {
  const int lane = threadIdx.x & 63;
  const int hi = lane >> 5, ql = lane & 31;
  // XCD-chunked swizzle: each XCD owns 8 consecutive bh (K+V ~4MB = one L2);
  // consecutive blocks on one XCD share bh -> K/V tiles L1-resident.
  int lin = blockIdx.x;                       // 4096 blocks
  int eff = (lin & 7) * 512 + (lin >> 3);
  const int bh = eff >> 6;                    // 64 q-chunks per bh
  const int q0 = (eff & 63) * 32;
  const char* kh = (const char*)(Kr + (size_t)bh * 2048 * 64);
  const char* vh = (const char*)(Vt + (size_t)bh * 64 * 2048);

  // Q B-frags: qf[t] = Q[q=q0+ql][d = t*16 + hi*8 .. +7]
  s16x8 qf[4];
  {
    const char* qrow = (const char*)Q + ((size_t)bh * 2048 + q0 + ql) * 128;
#pragma unroll
    for (int t = 0; t < 4; ++t) qf[t] = *(const s16x8*)(qrow + t * 32 + hi * 16);
  }

  // K frags: kf[2t+z] = K[kv = z*32 + ql][k-slice t] ; V frags: vf[2s+z] = V^T[d = z*32 + ql][..]
  const char* kb = kh + (size_t)ql * 128 + hi * 16;
  const char* vb = vh + (size_t)ql * 4096 + hi * 16;
  s16x8 kf[8], vf[8];
#pragma unroll
  for (int t = 0; t < 4; ++t) {
    kf[2 * t]     = *(const s16x8*)(kb + t * 32);
    kf[2 * t + 1] = *(const s16x8*)(kb + 32 * 128 + t * 32);
  }
#pragma unroll
  for (int s = 0; s < 4; ++s) {
    vf[2 * s]     = *(const s16x8*)(vb + s * 32);
    vf[2 * s + 1] = *(const s16x8*)(vb + 32 * 4096 + s * 32);
  }

  float l_run = 0.f;
  f32x16 oa0 = {}, oa1 = {};   // D[d][q]: d 0-31, d 32-63

  for (int it = 0; it < 32; ++it) {
    // QK^T: sc0 = S^T[kv 0-31][q], sc1 = S^T[kv 32-63][q]
    f32x16 sc0 = {}, sc1 = {};
    __builtin_amdgcn_s_setprio(1);
#pragma unroll
    for (int t = 0; t < 4; ++t) {
      sc0 = __builtin_amdgcn_mfma_f32_32x32x16_bf16(kf[2 * t],     qf[t], sc0, 0, 0, 0);
      sc1 = __builtin_amdgcn_mfma_f32_32x32x16_bf16(kf[2 * t + 1], qf[t], sc1, 0, 0, 0);
    }
    __builtin_amdgcn_s_setprio(0);
    __builtin_amdgcn_sched_barrier(0);   // pin next-K issue after QK cluster

    if (it + 1 < 32) {                   // issue K(it+1) into kf (regs free after QK)
      const char* kn = kb + (size_t)(it + 1) * 8192;
#pragma unroll
      for (int t = 0; t < 4; ++t) {
        kf[2 * t]     = *(const s16x8*)(kn + t * 32);
        kf[2 * t + 1] = *(const s16x8*)(kn + 32 * 128 + t * 32);
      }
    }

    // softmax (fixed m=0): p = exp2(s), lane-partial row sum
    float rs = 0.f;
#pragma unroll
    for (int r = 0; r < 16; ++r) { sc0[r] = __builtin_amdgcn_exp2f(sc0[r]); rs += sc0[r]; }
#pragma unroll
    for (int r = 0; r < 16; ++r) { sc1[r] = __builtin_amdgcn_exp2f(sc1[r]); rs += sc1[r]; }
    l_run += rs;

    // in-register P relayout: sc reg r holds kv=(r&3)+8*(r>>2)+4*hi -> B-frag layout
    unsigned int bp[16];
#pragma unroll
    for (int blk = 0; blk < 2; ++blk) {
      const f32x16& s = blk ? sc1 : sc0;
      unsigned int a0 = cvt_pk_bf16(s[0],  s[1]);
      unsigned int a1 = cvt_pk_bf16(s[2],  s[3]);
      unsigned int a2 = cvt_pk_bf16(s[4],  s[5]);
      unsigned int a3 = cvt_pk_bf16(s[6],  s[7]);
      pswap(a0, a2); pswap(a1, a3);
      bp[blk * 8 + 0] = a0; bp[blk * 8 + 1] = a1;
      bp[blk * 8 + 2] = a2; bp[blk * 8 + 3] = a3;
      unsigned int b0 = cvt_pk_bf16(s[8],  s[9]);
      unsigned int b1 = cvt_pk_bf16(s[10], s[11]);
      unsigned int b2 = cvt_pk_bf16(s[12], s[13]);
      unsigned int b3 = cvt_pk_bf16(s[14], s[15]);
      pswap(b0, b2); pswap(b1, b3);
      bp[blk * 8 + 4] = b0; bp[blk * 8 + 5] = b1;
      bp[blk * 8 + 6] = b2; bp[blk * 8 + 7] = b3;
    }

    // PV: oa[dblk] += V^T[d][kv] * P^T[kv][q]
    __builtin_amdgcn_s_setprio(1);
#pragma unroll
    for (int ss = 0; ss < 4; ++ss) {
      uint4 u = {bp[ss * 4], bp[ss * 4 + 1], bp[ss * 4 + 2], bp[ss * 4 + 3]};
      s16x8 pb = __builtin_bit_cast(s16x8, u);
      oa0 = __builtin_amdgcn_mfma_f32_32x32x16_bf16(vf[2 * ss],     pb, oa0, 0, 0, 0);
      oa1 = __builtin_amdgcn_mfma_f32_32x32x16_bf16(vf[2 * ss + 1], pb, oa1, 0, 0, 0);
    }
    __builtin_amdgcn_s_setprio(0);
    __builtin_amdgcn_sched_barrier(0);   // pin next-V issue after PV cluster

    if (it + 1 < 32) {                   // issue V(it+1) into vf
      const char* vn = vb + (size_t)(it + 1) * 128;
#pragma unroll
      for (int s = 0; s < 4; ++s) {
        vf[2 * s]     = *(const s16x8*)(vn + s * 32);
        vf[2 * s + 1] = *(const s16x8*)(vn + 32 * 4096 + s * 32);
      }
    }
  }

  // epilogue: partner-lane l sum, normalize, store ctx bf16
  l_run += __shfl_xor(l_run, 32);
  float inv = 1.f / l_run;
  const int b = bh >> 4, h = bh & 15;
  const int q = q0 + ql;
  unsigned short* crow = Ctx + ((size_t)(b * 2048 + q)) * 1024 + h * 64;
#pragma unroll
  for (int dblk = 0; dblk < 2; ++dblk) {
    const f32x16& oa = dblk ? oa1 : oa0;
#pragma unroll
    for (int grp = 0; grp < 4; ++grp) {
      ushort4 st;
      st.x = f2bf(oa[4 * grp + 0] * inv);
      st.y = f2bf(oa[4 * grp + 1] * inv);
      st.z = f2bf(oa[4 * grp + 2] * inv);
      st.w = f2bf(oa[4 * grp + 3] * inv);
      *(ushort4*)(crow + dblk * 32 + 8 * grp + 4 * hi) = st;
    }
  }
}

extern "C" void kernel_launch(void* const* d_in, const int* in_sizes, int n_in,
                              void* d_out, int out_size, void* d_ws, size_t ws_size,
                              hipStream_t stream) {
  const float* hidden = (const float*)d_in[0];   // (4,2048,1024) f32
  const int*   pos    = (const int*)d_in[1];     // (4,2048) i32
  const float* wqkv   = (const float*)d_in[2];   // (3072,1024) f32
  const float* wo     = (const float*)d_in[3];   // (1024,1024) f32

  char* ws = (char*)d_ws;
  unsigned short* hbf  = (unsigned short*)(ws);                 // 16,777,216 B
  unsigned short* wqbf = (unsigned short*)(ws + 16777216);      //  6,291,456
  unsigned short* wobf = (unsigned short*)(ws + 23068672);      //  2,097,152
  unsigned short* vbuf = (unsigned short*)(ws + 25165824);      // 16,777,216
  unsigned short* Qr   = (unsigned short*)(ws + 41943040);      // 16,777,216
  unsigned short* Kr   = (unsigned short*)(ws + 58720256);      // 16,777,216
  unsigned short* Vt   = (unsigned short*)(ws + 75497472);      // 16,777,216
  unsigned short* ctx  = (unsigned short*)(ws + 92274688);      // 16,777,216
  float*          ctab = (float*)(ws + 109051904);              //  1,048,576
  float*          stab = (float*)(ws + 110100480);              //  1,048,576
  // total: 111,149,056 B

  cvt_all_kernel<<<12288, 256, 0, stream>>>(hidden, wqkv, wo, hbf, wqbf, wobf);
  rope_table_kernel<<<1024, 256, 0, stream>>>(pos, ctab, stab);

  dim3 gq(64, 24);
  gemm_bt_kernel<2><<<gq, 256, 0, stream>>>(hbf, wqbf, nullptr, 3072, 1024,
                                            ctab, stab, Qr, Kr, vbuf);

  vtrans_kernel<<<2048, 256, 0, stream>>>(vbuf, Vt);

  attn_kernel<<<4096, 64, 0, stream>>>(Qr, Kr, Vt, ctx);

  dim3 go(64, 8);
  gemm_bt_kernel<1><<<go, 256, 0, stream>>>(ctx, wobf, d_out, 1024, 1024,
                                            nullptr, nullptr, nullptr, nullptr, nullptr);
}

// Round 10
// 215.235 us; speedup vs baseline: 1.5910x; 1.5910x over previous
//
#include <hip/hip_runtime.h>
#include <hip/hip_bf16.h>

// ModernBertAttention: B=4 S=2048 H=1024 NH=16 HD=64, rope theta=160000, f32 in/out.
// R10: R9 pipeline (triple-buffered K/V, one raw barrier, counted vmcnt) with the
//      prologue issue-order race fixed: vmcnt(0) on iteration 0 + sched_barrier(0)
//      pins between all prologue/in-loop STAGE issue points. Compute identical to R6.
//      GEMMs/vtrans/cvt unchanged.

#define GLOBAL_AS __attribute__((address_space(1)))
#define LDS_AS    __attribute__((address_space(3)))

using f32x4  = __attribute__((ext_vector_type(4))) float;
using f32x16 = __attribute__((ext_vector_type(16))) float;
using s16x8  = __attribute__((ext_vector_type(8))) short;

__device__ __forceinline__ void gld_lds16(const void* g, void* l) {
  __builtin_amdgcn_global_load_lds((const GLOBAL_AS void*)g, (LDS_AS void*)l, 16, 0, 0);
}

__device__ __forceinline__ unsigned short f2bf(float f) {
  unsigned int u = __float_as_uint(f);
  u = (u + 0x7fffu + ((u >> 16) & 1u)) >> 16;   // RNE
  return (unsigned short)u;
}
__device__ __forceinline__ unsigned int cvt_pk_bf16(float lo, float hi) {
  unsigned int r;
  asm("v_cvt_pk_bf16_f32 %0, %1, %2" : "=v"(r) : "v"(lo), "v"(hi));
  return r;
}
// swap hi32 lanes of a with lo32 lanes of b
__device__ __forceinline__ void pswap(unsigned int& a, unsigned int& b) {
  asm("v_permlane32_swap_b32 %0, %1" : "+v"(a), "+v"(b));
}

// ---------------- merged f32 -> bf16 convert (4 elems/thread) ----------------
__global__ __launch_bounds__(256) void cvt_all_kernel(const float* __restrict__ h,
                                                      const float* __restrict__ wq,
                                                      const float* __restrict__ wo,
                                                      unsigned short* __restrict__ hb,
                                                      unsigned short* __restrict__ wqb,
                                                      unsigned short* __restrict__ wob) {
  int b = blockIdx.x;
  const float* src; unsigned short* dst; int i;
  if (b < 8192)       { src = h;  dst = hb;  i = b * 256 + threadIdx.x; }
  else if (b < 11264) { src = wq; dst = wqb; i = (b - 8192) * 256 + threadIdx.x; }
  else                { src = wo; dst = wob; i = (b - 11264) * 256 + threadIdx.x; }
  float4 v = ((const float4*)src)[i];
  ushort4 o;
  o.x = f2bf(v.x); o.y = f2bf(v.y); o.z = f2bf(v.z); o.w = f2bf(v.w);
  ((ushort4*)dst)[i] = o;
}

// ---------------- rope cos/sin table: idx = (b*2048+s)*32 + d ----------------
__global__ __launch_bounds__(256) void rope_table_kernel(const int* __restrict__ pos,
                                                         float* __restrict__ ctab,
                                                         float* __restrict__ stab) {
  int idx = blockIdx.x * 256 + threadIdx.x;   // B*S*32 total
  int d = idx & 31;
  int bs = idx >> 5;
  float p = (float)pos[bs];
  float inv = exp2f(-(float)d * 0.5402410118609203f);  // theta^(-d/32)
  float f = p * inv;
  ctab[idx] = cosf(f);
  stab[idx] = sinf(f);
}

// ---------------- GEMM C[m,n] = sum_k A[m,k]*B[n,k], bf16 in, 128x128 tile, BK=64 ----------------
// MODE 1: f32 C store. MODE 2: fused QKV epilogue (rope -> Qr/Kr, V -> vbuf).
template<int MODE>
__global__ __launch_bounds__(256) void gemm_bt_kernel(const unsigned short* __restrict__ A,
                                                      const unsigned short* __restrict__ Bm,
                                                      void* __restrict__ C, int N, int K,
                                                      const float* __restrict__ ctab,
                                                      const float* __restrict__ stab,
                                                      unsigned short* __restrict__ Qr,
                                                      unsigned short* __restrict__ Kr,
                                                      unsigned short* __restrict__ vbuf) {
  __shared__ char sA[16384];   // 128 rows x 64 bf16 (128B rows), XOR-swizzled (row&7)<<4
  __shared__ char sB[16384];
  const int tid  = threadIdx.x;
  const int lane = tid & 63, w = tid >> 6;
  const int g = lane >> 4, c = lane & 15;
  const int wr = w >> 1, wc = w & 1;
  const int m0 = blockIdx.x * 128, n0 = blockIdx.y * 128;
  const char* Ab = (const char*)A;
  const char* Bb = (const char*)Bm;

  f32x4 acc[4][4] = {};
  for (int k0 = 0; k0 < K; k0 += 64) {
    __syncthreads();
#pragma unroll
    for (int rr = 0; rr < 4; ++rr) {
      int o = tid * 16 + rr * 4096;
      int row = o >> 7;
      int col = (o & 127) ^ ((row & 7) << 4);   // pre-swizzled source column
      gld_lds16(Ab + ((size_t)(m0 + row) * K + k0) * 2 + col, sA + o);
      gld_lds16(Bb + ((size_t)(n0 + row) * K + k0) * 2 + col, sB + o);
    }
    __syncthreads();
#pragma unroll
    for (int ks = 0; ks < 2; ++ks) {
      s16x8 af[4], bfr[4];
#pragma unroll
      for (int i = 0; i < 4; ++i) {
        int row = 64 * wr + 16 * i + c;
        af[i] = *(const s16x8*)(sA + ((row * 128 + ks * 64 + g * 16) ^ ((row & 7) << 4)));
      }
#pragma unroll
      for (int j = 0; j < 4; ++j) {
        int row = 64 * wc + 16 * j + c;
        bfr[j] = *(const s16x8*)(sB + ((row * 128 + ks * 64 + g * 16) ^ ((row & 7) << 4)));
      }
#pragma unroll
      for (int i = 0; i < 4; ++i)
#pragma unroll
        for (int j = 0; j < 4; ++j)
          acc[i][j] = __builtin_amdgcn_mfma_f32_16x16x32_bf16(af[i], bfr[j], acc[i][j], 0, 0, 0);
    }
  }

  if (MODE == 1) {
#pragma unroll
    for (int i = 0; i < 4; ++i)
#pragma unroll
      for (int j = 0; j < 4; ++j)
#pragma unroll
        for (int r = 0; r < 4; ++r) {
          int m = m0 + 64 * wr + 16 * i + 4 * g + r;
          int n = n0 + 64 * wc + 16 * j + c;
          ((float*)C)[(size_t)m * N + n] = acc[i][j][r];
        }
  } else {
    const int t = blockIdx.y;   // 0..7 Q, 8..15 K, 16..23 V
    if (t < 16) {
      unsigned short* dstb = (t < 8) ? Qr : Kr;
      const float qs = (t < 8) ? 0.18033688011112042f : 1.0f;  // SCALE*log2(e) on Q
      const int h = 2 * (t & 7) + wc;
#pragma unroll
      for (int i = 0; i < 4; ++i)
#pragma unroll
        for (int r = 0; r < 4; ++r) {
          int m = m0 + 64 * wr + 16 * i + 4 * g + r;
          int b = m >> 11, s = m & 2047;
          unsigned short* drow = dstb + ((size_t)(b * 16 + h) * 2048 + s) * 64;
#pragma unroll
          for (int j = 0; j < 2; ++j) {
            int d = 16 * j + c;
            float co = ctab[(size_t)m * 32 + d];
            float si = stab[(size_t)m * 32 + d];
            float x1 = acc[i][j][r], x2 = acc[i][j + 2][r];
            drow[d]      = f2bf((x1 * co - x2 * si) * qs);
            drow[d + 32] = f2bf((x2 * co + x1 * si) * qs);
          }
        }
    } else {
#pragma unroll
      for (int i = 0; i < 4; ++i)
#pragma unroll
        for (int j = 0; j < 4; ++j)
#pragma unroll
          for (int r = 0; r < 4; ++r) {
            int m = m0 + 64 * wr + 16 * i + 4 * g + r;
            int n = (t - 16) * 128 + 64 * wc + 16 * j + c;
            vbuf[(size_t)m * 1024 + n] = f2bf(acc[i][j][r]);
          }
    }
  }
}

// ---------------- V transpose: vbuf (B*S,1024) -> Vt (B,NH,64,S) ----------------
__global__ __launch_bounds__(256) void vtrans_kernel(const unsigned short* __restrict__ vbuf,
                                                     unsigned short* __restrict__ Vt) {
  __shared__ unsigned short tile[64][80];
  int bid = blockIdx.x;                      // b*16*32 + h*32 + st
  int st = bid & 31, h = (bid >> 5) & 15, b = bid >> 9;
  int s0 = st * 64;
  int t = threadIdx.x;
  {
    int row = t >> 2, part = t & 3;
    const unsigned short* src = vbuf + ((size_t)(b * 2048 + s0 + row)) * 1024 + h * 64 + part * 16;
    uint4 v0 = *(const uint4*)(src);
    uint4 v1 = *(const uint4*)(src + 8);
    *(uint4*)&tile[row][part * 16]     = v0;
    *(uint4*)&tile[row][part * 16 + 8] = v1;
  }
  __syncthreads();
  {
    int d = t >> 2, sp = t & 3;
    unsigned short vals[16];
#pragma unroll
    for (int i = 0; i < 16; ++i) vals[i] = tile[sp * 16 + i][d];
    unsigned short* dst = Vt + ((size_t)(b * 16 + h) * 64 + d) * 2048 + s0 + sp * 16;
    *(uint4*)(dst)     = ((const uint4*)vals)[0];
    *(uint4*)(dst + 8) = ((const uint4*)vals)[1];
  }
}

// ---------------- flash attention: 128 q/block, 4 waves, 32x32x16 MFMA ----------------
// Triple-buffered K/V; per iter: counted vmcnt (tile it only) -> s_barrier -> stage
// it+2 -> compute it. Issue order pinned: vmcnt(0) at it=0 covers prologue interleave.
__global__ __launch_bounds__(256) void attn_kernel(const unsigned short* __restrict__ Q,
                                                   const unsigned short* __restrict__ Kr,
                                                   const unsigned short* __restrict__ Vt,
                                                   unsigned short* __restrict__ Ctx) {
  __shared__ char sK[3][8192];   // 64 kv rows x 128B, swizzle (row&7)<<4
  __shared__ char sV[3][8192];   // 64 d rows x 128B (V^T tile)
  const int tid  = threadIdx.x;
  const int lane = tid & 63, w = tid >> 6;
  const int hi = lane >> 5, ql = lane & 31;
  const int swz = (ql & 7) << 4;
  // XCD-chunked swizzle: each XCD owns 8 consecutive bh (K+V ~4MB = one L2)
  int lin = blockIdx.x + 16 * blockIdx.y;            // grid (16, 64)
  int eff = (lin & 7) * 128 + (lin >> 3);
  const int bh = eff >> 4;
  const int q0 = (eff & 15) * 128;
  const char* kh = (const char*)(Kr + (size_t)bh * 2048 * 64);
  const char* vh = (const char*)(Vt + (size_t)bh * 64 * 2048);

  // Q B-frags: qf[t] = Q[q=q0+32w+ql][d = t*16 + hi*8 .. +7]
  s16x8 qf[4];
  {
    const char* qrow = (const char*)Q + ((size_t)bh * 2048 + q0 + 32 * w + ql) * 128;
#pragma unroll
    for (int t = 0; t < 4; ++t) qf[t] = *(const s16x8*)(qrow + t * 32 + hi * 16);
  }
  __builtin_amdgcn_sched_barrier(0);   // qf loads issued before any STAGE

  // stage tile t (kv rows t*64..t*64+63) into buffer b: 4 gld_lds16 per thread
#define STAGE(t, b)                                                              \
  {                                                                              \
    _Pragma("unroll")                                                            \
    for (int rr = 0; rr < 2; ++rr) {                                             \
      int o = tid * 16 + rr * 4096;                                              \
      int l = o ^ (((o >> 7) & 7) << 4);                                         \
      gld_lds16(kh + (size_t)(t) * 8192 + l, sK[b] + o);                         \
      gld_lds16(vh + (size_t)(o >> 7) * 4096 + (t) * 128 + (l & 127), sV[b] + o);\
    }                                                                            \
  }

  // prologue: tiles 0,1 into buffers 0,1 (issue order pinned)
  STAGE(0, 0);
  __builtin_amdgcn_sched_barrier(0);
  STAGE(1, 1);
  __builtin_amdgcn_sched_barrier(0);

  float l_run = 0.f;
  f32x16 oa0 = {}, oa1 = {};   // D[d][q]: d 0-31, d 32-63
  int cur = 0;

  for (int it = 0; it < 32; ++it) {
    // it=0: full drain (prologue issue order not tile-granular). it>=1: counted wait —
    // outstanding = {tile it (4, oldest), tile it+1 (4)}; vmcnt(4) completes tile it.
    if (it == 0 || it == 31) asm volatile("s_waitcnt vmcnt(0)" ::: "memory");
    else                     asm volatile("s_waitcnt vmcnt(4)" ::: "memory");
    __builtin_amdgcn_sched_barrier(0);
    __builtin_amdgcn_s_barrier();
    __builtin_amdgcn_sched_barrier(0);

    // stage tile it+2 into the buffer freed at iter it-1 (= (cur+2)%3)
    if (it + 2 < 32) {
      int sb = cur + 2; if (sb >= 3) sb -= 3;
      STAGE(it + 2, sb);
    }
    __builtin_amdgcn_sched_barrier(0);

    // QK^T: sc0 = S^T[kv 0-31][q], sc1 = S^T[kv 32-63][q]
    f32x16 sc0 = {}, sc1 = {};
    __builtin_amdgcn_s_setprio(1);
#pragma unroll
    for (int t = 0; t < 4; ++t) {
      int cx = (t * 32 + hi * 16) ^ swz;
      s16x8 k0 = *(const s16x8*)(sK[cur] + ql * 128 + cx);
      s16x8 k1 = *(const s16x8*)(sK[cur] + (32 + ql) * 128 + cx);
      sc0 = __builtin_amdgcn_mfma_f32_32x32x16_bf16(k0, qf[t], sc0, 0, 0, 0);
      sc1 = __builtin_amdgcn_mfma_f32_32x32x16_bf16(k1, qf[t], sc1, 0, 0, 0);
    }
    __builtin_amdgcn_s_setprio(0);

    // softmax (fixed m=0): p = exp2(s), lane-partial row sum
    float rs = 0.f;
#pragma unroll
    for (int r = 0; r < 16; ++r) { sc0[r] = __builtin_amdgcn_exp2f(sc0[r]); rs += sc0[r]; }
#pragma unroll
    for (int r = 0; r < 16; ++r) { sc1[r] = __builtin_amdgcn_exp2f(sc1[r]); rs += sc1[r]; }
    l_run += rs;

    // in-register P relayout: sc reg r holds kv=(r&3)+8*(r>>2)+4*hi -> B-frag layout
    unsigned int bp[16];
#pragma unroll
    for (int blk = 0; blk < 2; ++blk) {
      const f32x16& s = blk ? sc1 : sc0;
      unsigned int a0 = cvt_pk_bf16(s[0],  s[1]);
      unsigned int a1 = cvt_pk_bf16(s[2],  s[3]);
      unsigned int a2 = cvt_pk_bf16(s[4],  s[5]);
      unsigned int a3 = cvt_pk_bf16(s[6],  s[7]);
      pswap(a0, a2); pswap(a1, a3);
      bp[blk * 8 + 0] = a0; bp[blk * 8 + 1] = a1;
      bp[blk * 8 + 2] = a2; bp[blk * 8 + 3] = a3;
      unsigned int b0 = cvt_pk_bf16(s[8],  s[9]);
      unsigned int b1 = cvt_pk_bf16(s[10], s[11]);
      unsigned int b2 = cvt_pk_bf16(s[12], s[13]);
      unsigned int b3 = cvt_pk_bf16(s[14], s[15]);
      pswap(b0, b2); pswap(b1, b3);
      bp[blk * 8 + 4] = b0; bp[blk * 8 + 5] = b1;
      bp[blk * 8 + 6] = b2; bp[blk * 8 + 7] = b3;
    }

    // PV: oa[dblk] += V^T[d][kv] * P^T[kv][q]
    __builtin_amdgcn_s_setprio(1);
#pragma unroll
    for (int ss = 0; ss < 4; ++ss) {
      uint4 u = {bp[ss * 4], bp[ss * 4 + 1], bp[ss * 4 + 2], bp[ss * 4 + 3]};
      s16x8 pb = __builtin_bit_cast(s16x8, u);
      int cx = (ss * 32 + hi * 16) ^ swz;
      s16x8 v0 = *(const s16x8*)(sV[cur] + ql * 128 + cx);
      s16x8 v1 = *(const s16x8*)(sV[cur] + (32 + ql) * 128 + cx);
      oa0 = __builtin_amdgcn_mfma_f32_32x32x16_bf16(v0, pb, oa0, 0, 0, 0);
      oa1 = __builtin_amdgcn_mfma_f32_32x32x16_bf16(v1, pb, oa1, 0, 0, 0);
    }
    __builtin_amdgcn_s_setprio(0);

    ++cur; if (cur == 3) cur = 0;
  }
#undef STAGE

  // epilogue: partner lane (same q, other kv half) sum, normalize, store
  l_run += __shfl_xor(l_run, 32);
  float inv = 1.f / l_run;
  const int b = bh >> 4, h = bh & 15;
  const int q = q0 + 32 * w + ql;
  unsigned short* crow = Ctx + ((size_t)(b * 2048 + q)) * 1024 + h * 64;
#pragma unroll
  for (int dblk = 0; dblk < 2; ++dblk) {
    const f32x16& oa = dblk ? oa1 : oa0;
#pragma unroll
    for (int grp = 0; grp < 4; ++grp) {
      ushort4 st;
      st.x = f2bf(oa[4 * grp + 0] * inv);
      st.y = f2bf(oa[4 * grp + 1] * inv);
      st.z = f2bf(oa[4 * grp + 2] * inv);
      st.w = f2bf(oa[4 * grp + 3] * inv);
      *(ushort4*)(crow + dblk * 32 + 8 * grp + 4 * hi) = st;
    }
  }
}

extern "C" void kernel_launch(void* const* d_in, const int* in_sizes, int n_in,
                              void* d_out, int out_size, void* d_ws, size_t ws_size,
                              hipStream_t stream) {
  const float* hidden = (const float*)d_in[0];   // (4,2048,1024) f32
  const int*   pos    = (const int*)d_in[1];     // (4,2048) i32
  const float* wqkv   = (const float*)d_in[2];   // (3072,1024) f32
  const float* wo     = (const float*)d_in[3];   // (1024,1024) f32

  char* ws = (char*)d_ws;
  unsigned short* hbf  = (unsigned short*)(ws);                 // 16,777,216 B
  unsigned short* wqbf = (unsigned short*)(ws + 16777216);      //  6,291,456
  unsigned short* wobf = (unsigned short*)(ws + 23068672);      //  2,097,152
  unsigned short* vbuf = (unsigned short*)(ws + 25165824);      // 16,777,216
  unsigned short* Qr   = (unsigned short*)(ws + 41943040);      // 16,777,216
  unsigned short* Kr   = (unsigned short*)(ws + 58720256);      // 16,777,216
  unsigned short* Vt   = (unsigned short*)(ws + 75497472);      // 16,777,216
  unsigned short* ctx  = (unsigned short*)(ws + 92274688);      // 16,777,216
  float*          ctab = (float*)(ws + 109051904);              //  1,048,576
  float*          stab = (float*)(ws + 110100480);              //  1,048,576
  // total: 111,149,056 B

  cvt_all_kernel<<<12288, 256, 0, stream>>>(hidden, wqkv, wo, hbf, wqbf, wobf);
  rope_table_kernel<<<1024, 256, 0, stream>>>(pos, ctab, stab);

  dim3 gq(64, 24);
  gemm_bt_kernel<2><<<gq, 256, 0, stream>>>(hbf, wqbf, nullptr, 3072, 1024,
                                            ctab, stab, Qr, Kr, vbuf);

  vtrans_kernel<<<2048, 256, 0, stream>>>(vbuf, Vt);

  dim3 ga(16, 64);
  attn_kernel<<<ga, 256, 0, stream>>>(Qr, Kr, Vt, ctx);

  dim3 go(64, 8);
  gemm_bt_kernel<1><<<go, 256, 0, stream>>>(ctx, wobf, d_out, 1024, 1024,
                                            nullptr, nullptr, nullptr, nullptr, nullptr);
}

// Round 11
// 193.576 us; speedup vs baseline: 1.7690x; 1.1119x over previous
//
#include <hip/hip_runtime.h>
#include <hip/hip_bf16.h>

// ModernBertAttention: B=4 S=2048 H=1024 NH=16 HD=64, rope theta=160000, f32 in/out.
// R11: attn = 8 waves/block, QBLK=256 (2 blocks/CU exact, 16 waves/CU resident;
//      wave-level structure identical to R6/R10: 32q/wave, 32x32x16 MFMA, in-reg P).
//      Triple-buffered K/V, counted vmcnt(2), one raw barrier/iter.
//      GEMMs/vtrans/cvt unchanged.

#define GLOBAL_AS __attribute__((address_space(1)))
#define LDS_AS    __attribute__((address_space(3)))

using f32x4  = __attribute__((ext_vector_type(4))) float;
using f32x16 = __attribute__((ext_vector_type(16))) float;
using s16x8  = __attribute__((ext_vector_type(8))) short;

__device__ __forceinline__ void gld_lds16(const void* g, void* l) {
  __builtin_amdgcn_global_load_lds((const GLOBAL_AS void*)g, (LDS_AS void*)l, 16, 0, 0);
}

__device__ __forceinline__ unsigned short f2bf(float f) {
  unsigned int u = __float_as_uint(f);
  u = (u + 0x7fffu + ((u >> 16) & 1u)) >> 16;   // RNE
  return (unsigned short)u;
}
__device__ __forceinline__ unsigned int cvt_pk_bf16(float lo, float hi) {
  unsigned int r;
  asm("v_cvt_pk_bf16_f32 %0, %1, %2" : "=v"(r) : "v"(lo), "v"(hi));
  return r;
}
// swap hi32 lanes of a with lo32 lanes of b
__device__ __forceinline__ void pswap(unsigned int& a, unsigned int& b) {
  asm("v_permlane32_swap_b32 %0, %1" : "+v"(a), "+v"(b));
}

// ---------------- merged f32 -> bf16 convert (4 elems/thread) ----------------
__global__ __launch_bounds__(256) void cvt_all_kernel(const float* __restrict__ h,
                                                      const float* __restrict__ wq,
                                                      const float* __restrict__ wo,
                                                      unsigned short* __restrict__ hb,
                                                      unsigned short* __restrict__ wqb,
                                                      unsigned short* __restrict__ wob) {
  int b = blockIdx.x;
  const float* src; unsigned short* dst; int i;
  if (b < 8192)       { src = h;  dst = hb;  i = b * 256 + threadIdx.x; }
  else if (b < 11264) { src = wq; dst = wqb; i = (b - 8192) * 256 + threadIdx.x; }
  else                { src = wo; dst = wob; i = (b - 11264) * 256 + threadIdx.x; }
  float4 v = ((const float4*)src)[i];
  ushort4 o;
  o.x = f2bf(v.x); o.y = f2bf(v.y); o.z = f2bf(v.z); o.w = f2bf(v.w);
  ((ushort4*)dst)[i] = o;
}

// ---------------- rope cos/sin table: idx = (b*2048+s)*32 + d ----------------
__global__ __launch_bounds__(256) void rope_table_kernel(const int* __restrict__ pos,
                                                         float* __restrict__ ctab,
                                                         float* __restrict__ stab) {
  int idx = blockIdx.x * 256 + threadIdx.x;   // B*S*32 total
  int d = idx & 31;
  int bs = idx >> 5;
  float p = (float)pos[bs];
  float inv = exp2f(-(float)d * 0.5402410118609203f);  // theta^(-d/32)
  float f = p * inv;
  ctab[idx] = cosf(f);
  stab[idx] = sinf(f);
}

// ---------------- GEMM C[m,n] = sum_k A[m,k]*B[n,k], bf16 in, 128x128 tile, BK=64 ----------------
// MODE 1: f32 C store. MODE 2: fused QKV epilogue (rope -> Qr/Kr, V -> vbuf).
template<int MODE>
__global__ __launch_bounds__(256) void gemm_bt_kernel(const unsigned short* __restrict__ A,
                                                      const unsigned short* __restrict__ Bm,
                                                      void* __restrict__ C, int N, int K,
                                                      const float* __restrict__ ctab,
                                                      const float* __restrict__ stab,
                                                      unsigned short* __restrict__ Qr,
                                                      unsigned short* __restrict__ Kr,
                                                      unsigned short* __restrict__ vbuf) {
  __shared__ char sA[16384];   // 128 rows x 64 bf16 (128B rows), XOR-swizzled (row&7)<<4
  __shared__ char sB[16384];
  const int tid  = threadIdx.x;
  const int lane = tid & 63, w = tid >> 6;
  const int g = lane >> 4, c = lane & 15;
  const int wr = w >> 1, wc = w & 1;
  const int m0 = blockIdx.x * 128, n0 = blockIdx.y * 128;
  const char* Ab = (const char*)A;
  const char* Bb = (const char*)Bm;

  f32x4 acc[4][4] = {};
  for (int k0 = 0; k0 < K; k0 += 64) {
    __syncthreads();
#pragma unroll
    for (int rr = 0; rr < 4; ++rr) {
      int o = tid * 16 + rr * 4096;
      int row = o >> 7;
      int col = (o & 127) ^ ((row & 7) << 4);   // pre-swizzled source column
      gld_lds16(Ab + ((size_t)(m0 + row) * K + k0) * 2 + col, sA + o);
      gld_lds16(Bb + ((size_t)(n0 + row) * K + k0) * 2 + col, sB + o);
    }
    __syncthreads();
#pragma unroll
    for (int ks = 0; ks < 2; ++ks) {
      s16x8 af[4], bfr[4];
#pragma unroll
      for (int i = 0; i < 4; ++i) {
        int row = 64 * wr + 16 * i + c;
        af[i] = *(const s16x8*)(sA + ((row * 128 + ks * 64 + g * 16) ^ ((row & 7) << 4)));
      }
#pragma unroll
      for (int j = 0; j < 4; ++j) {
        int row = 64 * wc + 16 * j + c;
        bfr[j] = *(const s16x8*)(sB + ((row * 128 + ks * 64 + g * 16) ^ ((row & 7) << 4)));
      }
#pragma unroll
      for (int i = 0; i < 4; ++i)
#pragma unroll
        for (int j = 0; j < 4; ++j)
          acc[i][j] = __builtin_amdgcn_mfma_f32_16x16x32_bf16(af[i], bfr[j], acc[i][j], 0, 0, 0);
    }
  }

  if (MODE == 1) {
#pragma unroll
    for (int i = 0; i < 4; ++i)
#pragma unroll
      for (int j = 0; j < 4; ++j)
#pragma unroll
        for (int r = 0; r < 4; ++r) {
          int m = m0 + 64 * wr + 16 * i + 4 * g + r;
          int n = n0 + 64 * wc + 16 * j + c;
          ((float*)C)[(size_t)m * N + n] = acc[i][j][r];
        }
  } else {
    const int t = blockIdx.y;   // 0..7 Q, 8..15 K, 16..23 V
    if (t < 16) {
      unsigned short* dstb = (t < 8) ? Qr : Kr;
      const float qs = (t < 8) ? 0.18033688011112042f : 1.0f;  // SCALE*log2(e) on Q
      const int h = 2 * (t & 7) + wc;
#pragma unroll
      for (int i = 0; i < 4; ++i)
#pragma unroll
        for (int r = 0; r < 4; ++r) {
          int m = m0 + 64 * wr + 16 * i + 4 * g + r;
          int b = m >> 11, s = m & 2047;
          unsigned short* drow = dstb + ((size_t)(b * 16 + h) * 2048 + s) * 64;
#pragma unroll
          for (int j = 0; j < 2; ++j) {
            int d = 16 * j + c;
            float co = ctab[(size_t)m * 32 + d];
            float si = stab[(size_t)m * 32 + d];
            float x1 = acc[i][j][r], x2 = acc[i][j + 2][r];
            drow[d]      = f2bf((x1 * co - x2 * si) * qs);
            drow[d + 32] = f2bf((x2 * co + x1 * si) * qs);
          }
        }
    } else {
#pragma unroll
      for (int i = 0; i < 4; ++i)
#pragma unroll
        for (int j = 0; j < 4; ++j)
#pragma unroll
          for (int r = 0; r < 4; ++r) {
            int m = m0 + 64 * wr + 16 * i + 4 * g + r;
            int n = (t - 16) * 128 + 64 * wc + 16 * j + c;
            vbuf[(size_t)m * 1024 + n] = f2bf(acc[i][j][r]);
          }
    }
  }
}

// ---------------- V transpose: vbuf (B*S,1024) -> Vt (B,NH,64,S) ----------------
__global__ __launch_bounds__(256) void vtrans_kernel(const unsigned short* __restrict__ vbuf,
                                                     unsigned short* __restrict__ Vt) {
  __shared__ unsigned short tile[64][80];
  int bid = blockIdx.x;                      // b*16*32 + h*32 + st
  int st = bid & 31, h = (bid >> 5) & 15, b = bid >> 9;
  int s0 = st * 64;
  int t = threadIdx.x;
  {
    int row = t >> 2, part = t & 3;
    const unsigned short* src = vbuf + ((size_t)(b * 2048 + s0 + row)) * 1024 + h * 64 + part * 16;
    uint4 v0 = *(const uint4*)(src);
    uint4 v1 = *(const uint4*)(src + 8);
    *(uint4*)&tile[row][part * 16]     = v0;
    *(uint4*)&tile[row][part * 16 + 8] = v1;
  }
  __syncthreads();
  {
    int d = t >> 2, sp = t & 3;
    unsigned short vals[16];
#pragma unroll
    for (int i = 0; i < 16; ++i) vals[i] = tile[sp * 16 + i][d];
    unsigned short* dst = Vt + ((size_t)(b * 16 + h) * 64 + d) * 2048 + s0 + sp * 16;
    *(uint4*)(dst)     = ((const uint4*)vals)[0];
    *(uint4*)(dst + 8) = ((const uint4*)vals)[1];
  }
}

// ---------------- flash attention: 256 q/block, 8 waves x 32 q, 32x32x16 MFMA ----------------
// Triple-buffered K/V; counted vmcnt(2); one raw barrier/iter; in-reg P relayout.
// 512 blocks = 2/CU exact, 96KB LDS/CU -> 16 waves/CU resident.
__global__ __launch_bounds__(512) void attn_kernel(const unsigned short* __restrict__ Q,
                                                   const unsigned short* __restrict__ Kr,
                                                   const unsigned short* __restrict__ Vt,
                                                   unsigned short* __restrict__ Ctx) {
  __shared__ char sK[3][8192];   // 64 kv rows x 128B, swizzle (row&7)<<4
  __shared__ char sV[3][8192];   // 64 d rows x 128B (V^T tile)
  const int tid  = threadIdx.x;
  const int lane = tid & 63, w = tid >> 6;       // w in 0..7
  const int hi = lane >> 5, ql = lane & 31;
  const int swz = (ql & 7) << 4;
  // XCD-chunked swizzle: each XCD owns 8 consecutive bh (K+V ~2MB per XCD)
  int lin = blockIdx.x + 8 * blockIdx.y;         // grid (8, 64) = 512 blocks
  int eff = (lin & 7) * 64 + (lin >> 3);
  const int bh = eff >> 3;                       // 0..63
  const int q0 = (eff & 7) * 256;
  const char* kh = (const char*)(Kr + (size_t)bh * 2048 * 64);
  const char* vh = (const char*)(Vt + (size_t)bh * 64 * 2048);

  // Q B-frags: qf[t] = Q[q=q0+32w+ql][d = t*16 + hi*8 .. +7]
  s16x8 qf[4];
  {
    const char* qrow = (const char*)Q + ((size_t)bh * 2048 + q0 + 32 * w + ql) * 128;
#pragma unroll
    for (int t = 0; t < 4; ++t) qf[t] = *(const s16x8*)(qrow + t * 32 + hi * 16);
  }
  __builtin_amdgcn_sched_barrier(0);   // qf loads issued before any STAGE

  // stage tile t into buffer b: 512 threads cover 8KB in one pass (1 K + 1 V load/thread)
#define STAGE(t, b)                                                              \
  {                                                                              \
    int o = tid * 16;                                                            \
    int l = o ^ (((o >> 7) & 7) << 4);                                           \
    gld_lds16(kh + (size_t)(t) * 8192 + l, sK[b] + o);                           \
    gld_lds16(vh + (size_t)(o >> 7) * 4096 + (t) * 128 + (l & 127), sV[b] + o);  \
  }

  // prologue: tiles 0,1 into buffers 0,1 (issue order pinned)
  STAGE(0, 0);
  __builtin_amdgcn_sched_barrier(0);
  STAGE(1, 1);
  __builtin_amdgcn_sched_barrier(0);

  float l_run = 0.f;
  f32x16 oa0 = {}, oa1 = {};   // D[d][q]: d 0-31, d 32-63
  int cur = 0;

  for (int it = 0; it < 32; ++it) {
    // it=0: full drain (prologue order). it>=1: outstanding = {tile it (2, oldest),
    // tile it+1 (2)}; vmcnt(2) completes tile it, leaves it+1 in flight.
    if (it == 0 || it == 31) asm volatile("s_waitcnt vmcnt(0)" ::: "memory");
    else                     asm volatile("s_waitcnt vmcnt(2)" ::: "memory");
    __builtin_amdgcn_sched_barrier(0);
    __builtin_amdgcn_s_barrier();
    __builtin_amdgcn_sched_barrier(0);

    // stage tile it+2 into the buffer freed at iter it-1 (= (cur+2)%3)
    if (it + 2 < 32) {
      int sb = cur + 2; if (sb >= 3) sb -= 3;
      STAGE(it + 2, sb);
    }
    __builtin_amdgcn_sched_barrier(0);

    // QK^T: sc0 = S^T[kv 0-31][q], sc1 = S^T[kv 32-63][q]
    f32x16 sc0 = {}, sc1 = {};
    __builtin_amdgcn_s_setprio(1);
#pragma unroll
    for (int t = 0; t < 4; ++t) {
      int cx = (t * 32 + hi * 16) ^ swz;
      s16x8 k0 = *(const s16x8*)(sK[cur] + ql * 128 + cx);
      s16x8 k1 = *(const s16x8*)(sK[cur] + (32 + ql) * 128 + cx);
      sc0 = __builtin_amdgcn_mfma_f32_32x32x16_bf16(k0, qf[t], sc0, 0, 0, 0);
      sc1 = __builtin_amdgcn_mfma_f32_32x32x16_bf16(k1, qf[t], sc1, 0, 0, 0);
    }
    __builtin_amdgcn_s_setprio(0);

    // softmax (fixed m=0): p = exp2(s), lane-partial row sum
    float rs = 0.f;
#pragma unroll
    for (int r = 0; r < 16; ++r) { sc0[r] = __builtin_amdgcn_exp2f(sc0[r]); rs += sc0[r]; }
#pragma unroll
    for (int r = 0; r < 16; ++r) { sc1[r] = __builtin_amdgcn_exp2f(sc1[r]); rs += sc1[r]; }
    l_run += rs;

    // in-register P relayout: sc reg r holds kv=(r&3)+8*(r>>2)+4*hi -> B-frag layout
    unsigned int bp[16];
#pragma unroll
    for (int blk = 0; blk < 2; ++blk) {
      const f32x16& s = blk ? sc1 : sc0;
      unsigned int a0 = cvt_pk_bf16(s[0],  s[1]);
      unsigned int a1 = cvt_pk_bf16(s[2],  s[3]);
      unsigned int a2 = cvt_pk_bf16(s[4],  s[5]);
      unsigned int a3 = cvt_pk_bf16(s[6],  s[7]);
      pswap(a0, a2); pswap(a1, a3);
      bp[blk * 8 + 0] = a0; bp[blk * 8 + 1] = a1;
      bp[blk * 8 + 2] = a2; bp[blk * 8 + 3] = a3;
      unsigned int b0 = cvt_pk_bf16(s[8],  s[9]);
      unsigned int b1 = cvt_pk_bf16(s[10], s[11]);
      unsigned int b2 = cvt_pk_bf16(s[12], s[13]);
      unsigned int b3 = cvt_pk_bf16(s[14], s[15]);
      pswap(b0, b2); pswap(b1, b3);
      bp[blk * 8 + 4] = b0; bp[blk * 8 + 5] = b1;
      bp[blk * 8 + 6] = b2; bp[blk * 8 + 7] = b3;
    }

    // PV: oa[dblk] += V^T[d][kv] * P^T[kv][q]
    __builtin_amdgcn_s_setprio(1);
#pragma unroll
    for (int ss = 0; ss < 4; ++ss) {
      uint4 u = {bp[ss * 4], bp[ss * 4 + 1], bp[ss * 4 + 2], bp[ss * 4 + 3]};
      s16x8 pb = __builtin_bit_cast(s16x8, u);
      int cx = (ss * 32 + hi * 16) ^ swz;
      s16x8 v0 = *(const s16x8*)(sV[cur] + ql * 128 + cx);
      s16x8 v1 = *(const s16x8*)(sV[cur] + (32 + ql) * 128 + cx);
      oa0 = __builtin_amdgcn_mfma_f32_32x32x16_bf16(v0, pb, oa0, 0, 0, 0);
      oa1 = __builtin_amdgcn_mfma_f32_32x32x16_bf16(v1, pb, oa1, 0, 0, 0);
    }
    __builtin_amdgcn_s_setprio(0);

    ++cur; if (cur == 3) cur = 0;
  }
#undef STAGE

  // epilogue: partner lane (same q, other kv half) sum, normalize, store
  l_run += __shfl_xor(l_run, 32);
  float inv = 1.f / l_run;
  const int b = bh >> 4, h = bh & 15;
  const int q = q0 + 32 * w + ql;
  unsigned short* crow = Ctx + ((size_t)(b * 2048 + q)) * 1024 + h * 64;
#pragma unroll
  for (int dblk = 0; dblk < 2; ++dblk) {
    const f32x16& oa = dblk ? oa1 : oa0;
#pragma unroll
    for (int grp = 0; grp < 4; ++grp) {
      ushort4 st;
      st.x = f2bf(oa[4 * grp + 0] * inv);
      st.y = f2bf(oa[4 * grp + 1] * inv);
      st.z = f2bf(oa[4 * grp + 2] * inv);
      st.w = f2bf(oa[4 * grp + 3] * inv);
      *(ushort4*)(crow + dblk * 32 + 8 * grp + 4 * hi) = st;
    }
  }
}

extern "C" void kernel_launch(void* const* d_in, const int* in_sizes, int n_in,
                              void* d_out, int out_size, void* d_ws, size_t ws_size,
                              hipStream_t stream) {
  const float* hidden = (const float*)d_in[0];   // (4,2048,1024) f32
  const int*   pos    = (const int*)d_in[1];     // (4,2048) i32
  const float* wqkv   = (const float*)d_in[2];   // (3072,1024) f32
  const float* wo     = (const float*)d_in[3];   // (1024,1024) f32

  char* ws = (char*)d_ws;
  unsigned short* hbf  = (unsigned short*)(ws);                 // 16,777,216 B
  unsigned short* wqbf = (unsigned short*)(ws + 16777216);      //  6,291,456
  unsigned short* wobf = (unsigned short*)(ws + 23068672);      //  2,097,152
  unsigned short* vbuf = (unsigned short*)(ws + 25165824);      // 16,777,216
  unsigned short* Qr   = (unsigned short*)(ws + 41943040);      // 16,777,216
  unsigned short* Kr   = (unsigned short*)(ws + 58720256);      // 16,777,216
  unsigned short* Vt   = (unsigned short*)(ws + 75497472);      // 16,777,216
  unsigned short* ctx  = (unsigned short*)(ws + 92274688);      // 16,777,216
  float*          ctab = (float*)(ws + 109051904);              //  1,048,576
  float*          stab = (float*)(ws + 110100480);              //  1,048,576
  // total: 111,149,056 B

  cvt_all_kernel<<<12288, 256, 0, stream>>>(hidden, wqkv, wo, hbf, wqbf, wobf);
  rope_table_kernel<<<1024, 256, 0, stream>>>(pos, ctab, stab);

  dim3 gq(64, 24);
  gemm_bt_kernel<2><<<gq, 256, 0, stream>>>(hbf, wqbf, nullptr, 3072, 1024,
                                            ctab, stab, Qr, Kr, vbuf);

  vtrans_kernel<<<2048, 256, 0, stream>>>(vbuf, Vt);

  dim3 ga(8, 64);
  attn_kernel<<<ga, 512, 0, stream>>>(Qr, Kr, Vt, ctx);

  dim3 go(64, 8);
  gemm_bt_kernel<1><<<go, 256, 0, stream>>>(ctx, wobf, d_out, 1024, 1024,
                                            nullptr, nullptr, nullptr, nullptr, nullptr);
}

// Round 13
// 187.925 us; speedup vs baseline: 1.8222x; 1.0301x over previous
//
#include <hip/hip_runtime.h>
#include <hip/hip_bf16.h>

// ModernBertAttention: B=4 S=2048 H=1024 NH=16 HD=64, rope theta=160000, f32 in/out.
// R13: R12 with the V-epilogue indexing bug fixed (each thread covers 2 d-values;
//      R12 only wrote d<32, leaving half of Vt stale). attn frozen at R11 (83.5us).
//      vtrans eliminated; rope_table merged into cvt. 4 launches total.

#define GLOBAL_AS __attribute__((address_space(1)))
#define LDS_AS    __attribute__((address_space(3)))

using f32x4  = __attribute__((ext_vector_type(4))) float;
using f32x16 = __attribute__((ext_vector_type(16))) float;
using s16x8  = __attribute__((ext_vector_type(8))) short;

__device__ __forceinline__ void gld_lds16(const void* g, void* l) {
  __builtin_amdgcn_global_load_lds((const GLOBAL_AS void*)g, (LDS_AS void*)l, 16, 0, 0);
}

__device__ __forceinline__ unsigned short f2bf(float f) {
  unsigned int u = __float_as_uint(f);
  u = (u + 0x7fffu + ((u >> 16) & 1u)) >> 16;   // RNE
  return (unsigned short)u;
}
__device__ __forceinline__ unsigned int cvt_pk_bf16(float lo, float hi) {
  unsigned int r;
  asm("v_cvt_pk_bf16_f32 %0, %1, %2" : "=v"(r) : "v"(lo), "v"(hi));
  return r;
}
// swap hi32 lanes of a with lo32 lanes of b
__device__ __forceinline__ void pswap(unsigned int& a, unsigned int& b) {
  asm("v_permlane32_swap_b32 %0, %1" : "+v"(a), "+v"(b));
}

// ---------- merged f32->bf16 convert + rope table (blocks >= 12288) ----------
__global__ __launch_bounds__(256) void cvt_rope_kernel(const float* __restrict__ h,
                                                       const float* __restrict__ wq,
                                                       const float* __restrict__ wo,
                                                       const int* __restrict__ pos,
                                                       unsigned short* __restrict__ hb,
                                                       unsigned short* __restrict__ wqb,
                                                       unsigned short* __restrict__ wob,
                                                       float* __restrict__ ctab,
                                                       float* __restrict__ stab) {
  int b = blockIdx.x;
  if (b >= 12288) {   // rope table: B*S*32 entries
    int idx = (b - 12288) * 256 + threadIdx.x;
    int d = idx & 31;
    int bs = idx >> 5;
    float p = (float)pos[bs];
    float inv = exp2f(-(float)d * 0.5402410118609203f);  // theta^(-d/32)
    float f = p * inv;
    ctab[idx] = cosf(f);
    stab[idx] = sinf(f);
    return;
  }
  const float* src; unsigned short* dst; int i;
  if (b < 8192)       { src = h;  dst = hb;  i = b * 256 + threadIdx.x; }
  else if (b < 11264) { src = wq; dst = wqb; i = (b - 8192) * 256 + threadIdx.x; }
  else                { src = wo; dst = wob; i = (b - 11264) * 256 + threadIdx.x; }
  float4 v = ((const float4*)src)[i];
  ushort4 o;
  o.x = f2bf(v.x); o.y = f2bf(v.y); o.z = f2bf(v.z); o.w = f2bf(v.w);
  ((ushort4*)dst)[i] = o;
}

// ---------------- GEMM C[m,n] = sum_k A[m,k]*B[n,k], bf16 in, 128x128 tile, BK=64 ----------------
// MODE 1: f32 C store. MODE 2: fused QKV epilogue (rope -> Qr/Kr; V -> Vt via LDS transpose).
template<int MODE>
__global__ __launch_bounds__(256) void gemm_bt_kernel(const unsigned short* __restrict__ A,
                                                      const unsigned short* __restrict__ Bm,
                                                      void* __restrict__ C, int N, int K,
                                                      const float* __restrict__ ctab,
                                                      const float* __restrict__ stab,
                                                      unsigned short* __restrict__ Qr,
                                                      unsigned short* __restrict__ Kr,
                                                      unsigned short* __restrict__ Vt) {
  __shared__ char sAB[32768];
  char* sA = sAB;            // 128 rows x 64 bf16 (128B rows), XOR-swizzled (row&7)<<4
  char* sB = sAB + 16384;
  const int tid  = threadIdx.x;
  const int lane = tid & 63, w = tid >> 6;
  const int g = lane >> 4, c = lane & 15;
  const int wr = w >> 1, wc = w & 1;
  const int m0 = blockIdx.x * 128, n0 = blockIdx.y * 128;
  const char* Ab = (const char*)A;
  const char* Bb = (const char*)Bm;

  f32x4 acc[4][4] = {};
  for (int k0 = 0; k0 < K; k0 += 64) {
    __syncthreads();
#pragma unroll
    for (int rr = 0; rr < 4; ++rr) {
      int o = tid * 16 + rr * 4096;
      int row = o >> 7;
      int col = (o & 127) ^ ((row & 7) << 4);   // pre-swizzled source column
      gld_lds16(Ab + ((size_t)(m0 + row) * K + k0) * 2 + col, sA + o);
      gld_lds16(Bb + ((size_t)(n0 + row) * K + k0) * 2 + col, sB + o);
    }
    __syncthreads();
#pragma unroll
    for (int ks = 0; ks < 2; ++ks) {
      s16x8 af[4], bfr[4];
#pragma unroll
      for (int i = 0; i < 4; ++i) {
        int row = 64 * wr + 16 * i + c;
        af[i] = *(const s16x8*)(sA + ((row * 128 + ks * 64 + g * 16) ^ ((row & 7) << 4)));
      }
#pragma unroll
      for (int j = 0; j < 4; ++j) {
        int row = 64 * wc + 16 * j + c;
        bfr[j] = *(const s16x8*)(sB + ((row * 128 + ks * 64 + g * 16) ^ ((row & 7) << 4)));
      }
#pragma unroll
      for (int i = 0; i < 4; ++i)
#pragma unroll
        for (int j = 0; j < 4; ++j)
          acc[i][j] = __builtin_amdgcn_mfma_f32_16x16x32_bf16(af[i], bfr[j], acc[i][j], 0, 0, 0);
    }
  }

  if (MODE == 1) {
#pragma unroll
    for (int i = 0; i < 4; ++i)
#pragma unroll
      for (int j = 0; j < 4; ++j)
#pragma unroll
        for (int r = 0; r < 4; ++r) {
          int m = m0 + 64 * wr + 16 * i + 4 * g + r;
          int n = n0 + 64 * wc + 16 * j + c;
          ((float*)C)[(size_t)m * N + n] = acc[i][j][r];
        }
  } else {
    const int t = blockIdx.y;   // 0..7 Q, 8..15 K, 16..23 V
    if (t < 16) {
      unsigned short* dstb = (t < 8) ? Qr : Kr;
      const float qs = (t < 8) ? 0.18033688011112042f : 1.0f;  // SCALE*log2(e) on Q
      const int h = 2 * (t & 7) + wc;
#pragma unroll
      for (int i = 0; i < 4; ++i)
#pragma unroll
        for (int r = 0; r < 4; ++r) {
          int m = m0 + 64 * wr + 16 * i + 4 * g + r;
          int b = m >> 11, s = m & 2047;
          unsigned short* drow = dstb + ((size_t)(b * 16 + h) * 2048 + s) * 64;
#pragma unroll
          for (int j = 0; j < 2; ++j) {
            int d = 16 * j + c;
            float co = ctab[(size_t)m * 32 + d];
            float si = stab[(size_t)m * 32 + d];
            float x1 = acc[i][j][r], x2 = acc[i][j + 2][r];
            drow[d]      = f2bf((x1 * co - x2 * si) * qs);
            drow[d + 32] = f2bf((x2 * co + x1 * si) * qs);
          }
        }
    } else {
      // V epilogue: transpose via reused LDS, write Vt (B,NH,64,S) directly.
      // Two passes, one per head (wc selects which threads own the head's data).
      unsigned short (*tile)[74] = (unsigned short (*)[74])sAB;  // 128 s x 74 (pad)
      const int bb = m0 >> 11, sb = m0 & 2047;
#pragma unroll
      for (int hp = 0; hp < 2; ++hp) {
        __syncthreads();   // guards tile (overlaps sA/sB) vs trailing frag reads / prev pass
        if (wc == hp) {
#pragma unroll
          for (int i = 0; i < 4; ++i)
#pragma unroll
            for (int j = 0; j < 4; ++j)
#pragma unroll
              for (int r = 0; r < 4; ++r)
                tile[64 * wr + 16 * i + 4 * g + r][16 * j + c] = f2bf(acc[i][j][r]);
        }
        __syncthreads();
        int h = (t - 16) * 2 + hp;
        int p = tid & 7;                          // s-chunk 0..7 (16 s each)
#pragma unroll
        for (int dd = 0; dd < 2; ++dd) {          // each thread covers 2 d-values
          int d = (tid >> 3) + 32 * dd;           // d 0..63
          alignas(16) unsigned short vv[16];
#pragma unroll
          for (int i2 = 0; i2 < 16; ++i2) vv[i2] = tile[p * 16 + i2][d];
          unsigned short* dst = Vt + ((size_t)(bb * 16 + h) * 64 + d) * 2048 + sb + p * 16;
          *(uint4*)dst       = ((const uint4*)vv)[0];
          *(uint4*)(dst + 8) = ((const uint4*)vv)[1];
        }
      }
    }
  }
}

// ---------------- flash attention: 256 q/block, 8 waves x 32 q, 32x32x16 MFMA ----------------
// (frozen at R11) Triple-buffered K/V; counted vmcnt(2); one raw barrier/iter; in-reg P.
__global__ __launch_bounds__(512) void attn_kernel(const unsigned short* __restrict__ Q,
                                                   const unsigned short* __restrict__ Kr,
                                                   const unsigned short* __restrict__ Vt,
                                                   unsigned short* __restrict__ Ctx) {
  __shared__ char sK[3][8192];   // 64 kv rows x 128B, swizzle (row&7)<<4
  __shared__ char sV[3][8192];   // 64 d rows x 128B (V^T tile)
  const int tid  = threadIdx.x;
  const int lane = tid & 63, w = tid >> 6;       // w in 0..7
  const int hi = lane >> 5, ql = lane & 31;
  const int swz = (ql & 7) << 4;
  int lin = blockIdx.x + 8 * blockIdx.y;         // grid (8, 64) = 512 blocks
  int eff = (lin & 7) * 64 + (lin >> 3);
  const int bh = eff >> 3;                       // 0..63
  const int q0 = (eff & 7) * 256;
  const char* kh = (const char*)(Kr + (size_t)bh * 2048 * 64);
  const char* vh = (const char*)(Vt + (size_t)bh * 64 * 2048);

  s16x8 qf[4];
  {
    const char* qrow = (const char*)Q + ((size_t)bh * 2048 + q0 + 32 * w + ql) * 128;
#pragma unroll
    for (int t = 0; t < 4; ++t) qf[t] = *(const s16x8*)(qrow + t * 32 + hi * 16);
  }
  __builtin_amdgcn_sched_barrier(0);   // qf loads issued before any STAGE

#define STAGE(t, b)                                                              \
  {                                                                              \
    int o = tid * 16;                                                            \
    int l = o ^ (((o >> 7) & 7) << 4);                                           \
    gld_lds16(kh + (size_t)(t) * 8192 + l, sK[b] + o);                           \
    gld_lds16(vh + (size_t)(o >> 7) * 4096 + (t) * 128 + (l & 127), sV[b] + o);  \
  }

  STAGE(0, 0);
  __builtin_amdgcn_sched_barrier(0);
  STAGE(1, 1);
  __builtin_amdgcn_sched_barrier(0);

  float l_run = 0.f;
  f32x16 oa0 = {}, oa1 = {};   // D[d][q]: d 0-31, d 32-63
  int cur = 0;

  for (int it = 0; it < 32; ++it) {
    if (it == 0 || it == 31) asm volatile("s_waitcnt vmcnt(0)" ::: "memory");
    else                     asm volatile("s_waitcnt vmcnt(2)" ::: "memory");
    __builtin_amdgcn_sched_barrier(0);
    __builtin_amdgcn_s_barrier();
    __builtin_amdgcn_sched_barrier(0);

    if (it + 2 < 32) {
      int sb = cur + 2; if (sb >= 3) sb -= 3;
      STAGE(it + 2, sb);
    }
    __builtin_amdgcn_sched_barrier(0);

    f32x16 sc0 = {}, sc1 = {};
    __builtin_amdgcn_s_setprio(1);
#pragma unroll
    for (int t = 0; t < 4; ++t) {
      int cx = (t * 32 + hi * 16) ^ swz;
      s16x8 k0 = *(const s16x8*)(sK[cur] + ql * 128 + cx);
      s16x8 k1 = *(const s16x8*)(sK[cur] + (32 + ql) * 128 + cx);
      sc0 = __builtin_amdgcn_mfma_f32_32x32x16_bf16(k0, qf[t], sc0, 0, 0, 0);
      sc1 = __builtin_amdgcn_mfma_f32_32x32x16_bf16(k1, qf[t], sc1, 0, 0, 0);
    }
    __builtin_amdgcn_s_setprio(0);

    float rs = 0.f;
#pragma unroll
    for (int r = 0; r < 16; ++r) { sc0[r] = __builtin_amdgcn_exp2f(sc0[r]); rs += sc0[r]; }
#pragma unroll
    for (int r = 0; r < 16; ++r) { sc1[r] = __builtin_amdgcn_exp2f(sc1[r]); rs += sc1[r]; }
    l_run += rs;

    unsigned int bp[16];
#pragma unroll
    for (int blk = 0; blk < 2; ++blk) {
      const f32x16& s = blk ? sc1 : sc0;
      unsigned int a0 = cvt_pk_bf16(s[0],  s[1]);
      unsigned int a1 = cvt_pk_bf16(s[2],  s[3]);
      unsigned int a2 = cvt_pk_bf16(s[4],  s[5]);
      unsigned int a3 = cvt_pk_bf16(s[6],  s[7]);
      pswap(a0, a2); pswap(a1, a3);
      bp[blk * 8 + 0] = a0; bp[blk * 8 + 1] = a1;
      bp[blk * 8 + 2] = a2; bp[blk * 8 + 3] = a3;
      unsigned int b0 = cvt_pk_bf16(s[8],  s[9]);
      unsigned int b1 = cvt_pk_bf16(s[10], s[11]);
      unsigned int b2 = cvt_pk_bf16(s[12], s[13]);
      unsigned int b3 = cvt_pk_bf16(s[14], s[15]);
      pswap(b0, b2); pswap(b1, b3);
      bp[blk * 8 + 4] = b0; bp[blk * 8 + 5] = b1;
      bp[blk * 8 + 6] = b2; bp[blk * 8 + 7] = b3;
    }

    __builtin_amdgcn_s_setprio(1);
#pragma unroll
    for (int ss = 0; ss < 4; ++ss) {
      uint4 u = {bp[ss * 4], bp[ss * 4 + 1], bp[ss * 4 + 2], bp[ss * 4 + 3]};
      s16x8 pb = __builtin_bit_cast(s16x8, u);
      int cx = (ss * 32 + hi * 16) ^ swz;
      s16x8 v0 = *(const s16x8*)(sV[cur] + ql * 128 + cx);
      s16x8 v1 = *(const s16x8*)(sV[cur] + (32 + ql) * 128 + cx);
      oa0 = __builtin_amdgcn_mfma_f32_32x32x16_bf16(v0, pb, oa0, 0, 0, 0);
      oa1 = __builtin_amdgcn_mfma_f32_32x32x16_bf16(v1, pb, oa1, 0, 0, 0);
    }
    __builtin_amdgcn_s_setprio(0);

    ++cur; if (cur == 3) cur = 0;
  }
#undef STAGE

  l_run += __shfl_xor(l_run, 32);
  float inv = 1.f / l_run;
  const int b = bh >> 4, h = bh & 15;
  const int q = q0 + 32 * w + ql;
  unsigned short* crow = Ctx + ((size_t)(b * 2048 + q)) * 1024 + h * 64;
#pragma unroll
  for (int dblk = 0; dblk < 2; ++dblk) {
    const f32x16& oa = dblk ? oa1 : oa0;
#pragma unroll
    for (int grp = 0; grp < 4; ++grp) {
      ushort4 st;
      st.x = f2bf(oa[4 * grp + 0] * inv);
      st.y = f2bf(oa[4 * grp + 1] * inv);
      st.z = f2bf(oa[4 * grp + 2] * inv);
      st.w = f2bf(oa[4 * grp + 3] * inv);
      *(ushort4*)(crow + dblk * 32 + 8 * grp + 4 * hi) = st;
    }
  }
}

extern "C" void kernel_launch(void* const* d_in, const int* in_sizes, int n_in,
                              void* d_out, int out_size, void* d_ws, size_t ws_size,
                              hipStream_t stream) {
  const float* hidden = (const float*)d_in[0];   // (4,2048,1024) f32
  const int*   pos    = (const int*)d_in[1];     // (4,2048) i32
  const float* wqkv   = (const float*)d_in[2];   // (3072,1024) f32
  const float* wo     = (const float*)d_in[3];   // (1024,1024) f32

  char* ws = (char*)d_ws;
  unsigned short* hbf  = (unsigned short*)(ws);                 // 16,777,216 B
  unsigned short* wqbf = (unsigned short*)(ws + 16777216);      //  6,291,456
  unsigned short* wobf = (unsigned short*)(ws + 23068672);      //  2,097,152
  unsigned short* Qr   = (unsigned short*)(ws + 41943040);      // 16,777,216
  unsigned short* Kr   = (unsigned short*)(ws + 58720256);      // 16,777,216
  unsigned short* Vt   = (unsigned short*)(ws + 75497472);      // 16,777,216
  unsigned short* ctx  = (unsigned short*)(ws + 92274688);      // 16,777,216
  float*          ctab = (float*)(ws + 109051904);              //  1,048,576
  float*          stab = (float*)(ws + 110100480);              //  1,048,576
  // total: 111,149,056 B

  cvt_rope_kernel<<<13312, 256, 0, stream>>>(hidden, wqkv, wo, pos,
                                             hbf, wqbf, wobf, ctab, stab);

  dim3 gq(64, 24);
  gemm_bt_kernel<2><<<gq, 256, 0, stream>>>(hbf, wqbf, nullptr, 3072, 1024,
                                            ctab, stab, Qr, Kr, Vt);

  dim3 ga(8, 64);
  attn_kernel<<<ga, 512, 0, stream>>>(Qr, Kr, Vt, ctx);

  dim3 go(64, 8);
  gemm_bt_kernel<1><<<go, 256, 0, stream>>>(ctx, wobf, d_out, 1024, 1024,
                                            nullptr, nullptr, nullptr, nullptr, nullptr);
}

// Round 14
// 184.930 us; speedup vs baseline: 1.8517x; 1.0162x over previous
//
#include <hip/hip_runtime.h>
#include <hip/hip_bf16.h>

// ModernBertAttention: B=4 S=2048 H=1024 NH=16 HD=64, rope theta=160000, f32 in/out.
// R14: GEMMs ported to 256x128-tile / 8-wave / counted-vmcnt(3) pipeline (loads stay
//      in flight across K-tile barriers; 96KB dynamic LDS; CU-exact grids 768/256).
//      attn frozen at R11/R13 (83.5us). cvt_rope unchanged. 4 launches.

#define GLOBAL_AS __attribute__((address_space(1)))
#define LDS_AS    __attribute__((address_space(3)))

using f32x4  = __attribute__((ext_vector_type(4))) float;
using f32x16 = __attribute__((ext_vector_type(16))) float;
using s16x8  = __attribute__((ext_vector_type(8))) short;

__device__ __forceinline__ void gld_lds16(const void* g, void* l) {
  __builtin_amdgcn_global_load_lds((const GLOBAL_AS void*)g, (LDS_AS void*)l, 16, 0, 0);
}

__device__ __forceinline__ unsigned short f2bf(float f) {
  unsigned int u = __float_as_uint(f);
  u = (u + 0x7fffu + ((u >> 16) & 1u)) >> 16;   // RNE
  return (unsigned short)u;
}
__device__ __forceinline__ unsigned int cvt_pk_bf16(float lo, float hi) {
  unsigned int r;
  asm("v_cvt_pk_bf16_f32 %0, %1, %2" : "=v"(r) : "v"(lo), "v"(hi));
  return r;
}
__device__ __forceinline__ void pswap(unsigned int& a, unsigned int& b) {
  asm("v_permlane32_swap_b32 %0, %1" : "+v"(a), "+v"(b));
}

// ---------- merged f32->bf16 convert + rope table (blocks >= 12288) ----------
__global__ __launch_bounds__(256) void cvt_rope_kernel(const float* __restrict__ h,
                                                       const float* __restrict__ wq,
                                                       const float* __restrict__ wo,
                                                       const int* __restrict__ pos,
                                                       unsigned short* __restrict__ hb,
                                                       unsigned short* __restrict__ wqb,
                                                       unsigned short* __restrict__ wob,
                                                       float* __restrict__ ctab,
                                                       float* __restrict__ stab) {
  int b = blockIdx.x;
  if (b >= 12288) {   // rope table: B*S*32 entries
    int idx = (b - 12288) * 256 + threadIdx.x;
    int d = idx & 31;
    int bs = idx >> 5;
    float p = (float)pos[bs];
    float inv = exp2f(-(float)d * 0.5402410118609203f);  // theta^(-d/32)
    float f = p * inv;
    ctab[idx] = cosf(f);
    stab[idx] = sinf(f);
    return;
  }
  const float* src; unsigned short* dst; int i;
  if (b < 8192)       { src = h;  dst = hb;  i = b * 256 + threadIdx.x; }
  else if (b < 11264) { src = wq; dst = wqb; i = (b - 8192) * 256 + threadIdx.x; }
  else                { src = wo; dst = wob; i = (b - 11264) * 256 + threadIdx.x; }
  float4 v = ((const float4*)src)[i];
  ushort4 o;
  o.x = f2bf(v.x); o.y = f2bf(v.y); o.z = f2bf(v.z); o.w = f2bf(v.w);
  ((ushort4*)dst)[i] = o;
}

// ------- GEMM C[m,n]=sum_k A[m,k]B[n,k]: 256x128 tile, 8 waves (4Mx2N), BK=64 -------
// Double-buffered half-tile staging with counted vmcnt(3): after each K-tile's end
// barrier, the next-next tile's first halves are staged into the freed buffer, so
// 3 loads stay in flight across every boundary wait.
// MODE 1: f32 C. MODE 2: fused QKV epilogue (rope -> Qr/Kr; V -> Vt via LDS transpose).
template<int MODE>
__global__ __launch_bounds__(512) void gemm2_kernel(const unsigned short* __restrict__ A,
                                                    const unsigned short* __restrict__ Bm,
                                                    void* __restrict__ C, int N, int K,
                                                    const float* __restrict__ ctab,
                                                    const float* __restrict__ stab,
                                                    unsigned short* __restrict__ Qr,
                                                    unsigned short* __restrict__ Kr,
                                                    unsigned short* __restrict__ Vt) {
  extern __shared__ char lds[];   // 98304 B: 2 dbuf x (A 2x16KB + B 2x8KB)
  const int tid  = threadIdx.x;
  const int lane = tid & 63, w = tid >> 6;   // 8 waves
  const int g = lane >> 4, c = lane & 15;
  const int wr = w >> 1, wc = w & 1;         // wave tile: rows wr*64, cols wc*64
  const int m0 = blockIdx.x * 256, n0 = blockIdx.y * 128;
  const char* Ab = (const char*)A;
  const char* Bb = (const char*)Bm;
  const int NKT = K >> 6;                    // 16

  // stage A-half h (128 rows x 64 k = 16KB, 2 loads/thread) of K-tile kt
#define STAGE_A(kt, hh)                                                          \
  {                                                                              \
    _Pragma("unroll")                                                            \
    for (int L = 0; L < 2; ++L) {                                                \
      int o = tid * 16 + L * 8192;                                               \
      int row = o >> 7;                                                          \
      int gcol = (o & 127) ^ ((row & 7) << 4);                                   \
      gld_lds16(Ab + ((size_t)(m0 + (hh) * 128 + row) * K + (kt) * 64) * 2 + gcol,\
                lds + ((kt) & 1) * 49152 + (hh) * 16384 + o);                    \
    }                                                                            \
  }
  // stage B-half h (64 rows x 64 k = 8KB, 1 load/thread)
#define STAGE_B(kt, hh)                                                          \
  {                                                                              \
    int o = tid * 16;                                                            \
    int row = o >> 7;                                                            \
    int gcol = (o & 127) ^ ((row & 7) << 4);                                     \
    gld_lds16(Bb + ((size_t)(n0 + (hh) * 64 + row) * K + (kt) * 64) * 2 + gcol,  \
              lds + ((kt) & 1) * 49152 + 32768 + (hh) * 8192 + o);               \
  }

  // prologue: kt0 complete, then kt1 first halves (group order pinned)
  STAGE_A(0, 0); STAGE_B(0, 0); STAGE_A(0, 1); STAGE_B(0, 1);
  __builtin_amdgcn_sched_barrier(0);
  STAGE_A(1, 0); STAGE_B(1, 0);
  __builtin_amdgcn_sched_barrier(0);

  f32x4 acc[4][4] = {};
  const int rA0 = (wr & 1) * 64 + c;   // A row within half (half = wr>>1)
  for (int kt = 0; kt < NKT; ++kt) {
    // boundary: wait kt's 6 loads (oldest), leave next tile's 3 in flight
    if (kt == NKT - 1) asm volatile("s_waitcnt vmcnt(0)" ::: "memory");
    else               asm volatile("s_waitcnt vmcnt(3)" ::: "memory");
    __builtin_amdgcn_sched_barrier(0);
    __builtin_amdgcn_s_barrier();
    __builtin_amdgcn_sched_barrier(0);

    const char* baseA = lds + (kt & 1) * 49152 + (wr >> 1) * 16384;
    const char* baseB = lds + (kt & 1) * 49152 + 32768 + wc * 8192;

    s16x8 af[4][2], bf[4][2];
#pragma unroll
    for (int i = 0; i < 4; ++i) {
      int row = rA0 + 16 * i;
#pragma unroll
      for (int ks = 0; ks < 2; ++ks)
        af[i][ks] = *(const s16x8*)(baseA + ((row * 128 + ks * 64 + g * 16) ^ ((row & 7) << 4)));
    }
#pragma unroll
    for (int j = 0; j < 4; ++j) {
      int row = 16 * j + c;
#pragma unroll
      for (int ks = 0; ks < 2; ++ks)
        bf[j][ks] = *(const s16x8*)(baseB + ((row * 128 + ks * 64 + g * 16) ^ ((row & 7) << 4)));
    }

    if (kt + 1 < NKT) {   // stage kt+1's second halves (other dbuf; no race)
      STAGE_A(kt + 1, 1);
      STAGE_B(kt + 1, 1);
    }
    __builtin_amdgcn_sched_barrier(0);

    __builtin_amdgcn_s_setprio(1);
#pragma unroll
    for (int ks = 0; ks < 2; ++ks)
#pragma unroll
      for (int i = 0; i < 4; ++i)
#pragma unroll
        for (int j = 0; j < 4; ++j)
          acc[i][j] = __builtin_amdgcn_mfma_f32_16x16x32_bf16(af[i][ks], bf[j][ks], acc[i][j], 0, 0, 0);
    __builtin_amdgcn_s_setprio(0);

    __builtin_amdgcn_sched_barrier(0);
    __builtin_amdgcn_s_barrier();   // all waves done reading dbuf[kt&1]
    __builtin_amdgcn_sched_barrier(0);
    if (kt + 2 < NKT) {             // restage freed buffer: kt+2's first halves
      STAGE_A(kt + 2, 0);
      STAGE_B(kt + 2, 0);
      __builtin_amdgcn_sched_barrier(0);
    }
  }
#undef STAGE_A
#undef STAGE_B

  if (MODE == 1) {
#pragma unroll
    for (int i = 0; i < 4; ++i)
#pragma unroll
      for (int j = 0; j < 4; ++j)
#pragma unroll
        for (int r = 0; r < 4; ++r) {
          int m = m0 + wr * 64 + 16 * i + 4 * g + r;
          int n = n0 + wc * 64 + 16 * j + c;
          ((float*)C)[(size_t)m * N + n] = acc[i][j][r];
        }
  } else {
    const int t = blockIdx.y;   // 0..7 Q, 8..15 K, 16..23 V (128 cols each)
    if (t < 16) {
      unsigned short* dstb = (t < 8) ? Qr : Kr;
      const float qs = (t < 8) ? 0.18033688011112042f : 1.0f;  // SCALE*log2(e) on Q
      const int h = 2 * (t & 7) + wc;
#pragma unroll
      for (int i = 0; i < 4; ++i)
#pragma unroll
        for (int r = 0; r < 4; ++r) {
          int m = m0 + wr * 64 + 16 * i + 4 * g + r;
          int b = m >> 11, s = m & 2047;
          unsigned short* drow = dstb + ((size_t)(b * 16 + h) * 2048 + s) * 64;
#pragma unroll
          for (int j = 0; j < 2; ++j) {
            int d = 16 * j + c;
            float co = ctab[(size_t)m * 32 + d];
            float si = stab[(size_t)m * 32 + d];
            float x1 = acc[i][j][r], x2 = acc[i][j + 2][r];
            drow[d]      = f2bf((x1 * co - x2 * si) * qs);
            drow[d + 32] = f2bf((x2 * co + x1 * si) * qs);
          }
        }
    } else {
      // V epilogue: 2 heads/block (head = wc); transpose 256s x 64d via LDS.
      // tile uses lds[0..36864) = dbuf0; final K-tile (kt=15, odd) read dbuf1 -> no overlap.
      unsigned short (*tile)[72] = (unsigned short (*)[72])lds;
      const int bb = m0 >> 11, sb = m0 & 2047;
#pragma unroll
      for (int hp = 0; hp < 2; ++hp) {
        __syncthreads();
        if (wc == hp) {
#pragma unroll
          for (int i = 0; i < 4; ++i)
#pragma unroll
            for (int j = 0; j < 4; ++j)
#pragma unroll
              for (int r = 0; r < 4; ++r)
                tile[wr * 64 + 16 * i + 4 * g + r][16 * j + c] = f2bf(acc[i][j][r]);
        }
        __syncthreads();
        int hh = 2 * (t - 16) + hp;
        int d = tid >> 3, p = tid & 7;           // d 0..63, p = s-chunk (32 s each)
        alignas(16) unsigned short vv[32];
#pragma unroll
        for (int i2 = 0; i2 < 32; ++i2) vv[i2] = tile[p * 32 + i2][d];
        unsigned short* dst = Vt + ((size_t)(bb * 16 + hh) * 64 + d) * 2048 + sb + p * 32;
#pragma unroll
        for (int q4 = 0; q4 < 4; ++q4)
          *(uint4*)(dst + 8 * q4) = ((const uint4*)vv)[q4];
      }
    }
  }
}

// ---------------- flash attention: 256 q/block, 8 waves x 32 q, 32x32x16 MFMA ----------------
// (frozen at R11/R13) Triple-buffered K/V; counted vmcnt(2); one raw barrier/iter; in-reg P.
__global__ __launch_bounds__(512) void attn_kernel(const unsigned short* __restrict__ Q,
                                                   const unsigned short* __restrict__ Kr,
                                                   const unsigned short* __restrict__ Vt,
                                                   unsigned short* __restrict__ Ctx) {
  __shared__ char sK[3][8192];   // 64 kv rows x 128B, swizzle (row&7)<<4
  __shared__ char sV[3][8192];   // 64 d rows x 128B (V^T tile)
  const int tid  = threadIdx.x;
  const int lane = tid & 63, w = tid >> 6;       // w in 0..7
  const int hi = lane >> 5, ql = lane & 31;
  const int swz = (ql & 7) << 4;
  int lin = blockIdx.x + 8 * blockIdx.y;         // grid (8, 64) = 512 blocks
  int eff = (lin & 7) * 64 + (lin >> 3);
  const int bh = eff >> 3;                       // 0..63
  const int q0 = (eff & 7) * 256;
  const char* kh = (const char*)(Kr + (size_t)bh * 2048 * 64);
  const char* vh = (const char*)(Vt + (size_t)bh * 64 * 2048);

  s16x8 qf[4];
  {
    const char* qrow = (const char*)Q + ((size_t)bh * 2048 + q0 + 32 * w + ql) * 128;
#pragma unroll
    for (int t = 0; t < 4; ++t) qf[t] = *(const s16x8*)(qrow + t * 32 + hi * 16);
  }
  __builtin_amdgcn_sched_barrier(0);   // qf loads issued before any STAGE

#define STAGE(t, b)                                                              \
  {                                                                              \
    int o = tid * 16;                                                            \
    int l = o ^ (((o >> 7) & 7) << 4);                                           \
    gld_lds16(kh + (size_t)(t) * 8192 + l, sK[b] + o);                           \
    gld_lds16(vh + (size_t)(o >> 7) * 4096 + (t) * 128 + (l & 127), sV[b] + o);  \
  }

  STAGE(0, 0);
  __builtin_amdgcn_sched_barrier(0);
  STAGE(1, 1);
  __builtin_amdgcn_sched_barrier(0);

  float l_run = 0.f;
  f32x16 oa0 = {}, oa1 = {};   // D[d][q]: d 0-31, d 32-63
  int cur = 0;

  for (int it = 0; it < 32; ++it) {
    if (it == 0 || it == 31) asm volatile("s_waitcnt vmcnt(0)" ::: "memory");
    else                     asm volatile("s_waitcnt vmcnt(2)" ::: "memory");
    __builtin_amdgcn_sched_barrier(0);
    __builtin_amdgcn_s_barrier();
    __builtin_amdgcn_sched_barrier(0);

    if (it + 2 < 32) {
      int sb = cur + 2; if (sb >= 3) sb -= 3;
      STAGE(it + 2, sb);
    }
    __builtin_amdgcn_sched_barrier(0);

    f32x16 sc0 = {}, sc1 = {};
    __builtin_amdgcn_s_setprio(1);
#pragma unroll
    for (int t = 0; t < 4; ++t) {
      int cx = (t * 32 + hi * 16) ^ swz;
      s16x8 k0 = *(const s16x8*)(sK[cur] + ql * 128 + cx);
      s16x8 k1 = *(const s16x8*)(sK[cur] + (32 + ql) * 128 + cx);
      sc0 = __builtin_amdgcn_mfma_f32_32x32x16_bf16(k0, qf[t], sc0, 0, 0, 0);
      sc1 = __builtin_amdgcn_mfma_f32_32x32x16_bf16(k1, qf[t], sc1, 0, 0, 0);
    }
    __builtin_amdgcn_s_setprio(0);

    float rs = 0.f;
#pragma unroll
    for (int r = 0; r < 16; ++r) { sc0[r] = __builtin_amdgcn_exp2f(sc0[r]); rs += sc0[r]; }
#pragma unroll
    for (int r = 0; r < 16; ++r) { sc1[r] = __builtin_amdgcn_exp2f(sc1[r]); rs += sc1[r]; }
    l_run += rs;

    unsigned int bp[16];
#pragma unroll
    for (int blk = 0; blk < 2; ++blk) {
      const f32x16& s = blk ? sc1 : sc0;
      unsigned int a0 = cvt_pk_bf16(s[0],  s[1]);
      unsigned int a1 = cvt_pk_bf16(s[2],  s[3]);
      unsigned int a2 = cvt_pk_bf16(s[4],  s[5]);
      unsigned int a3 = cvt_pk_bf16(s[6],  s[7]);
      pswap(a0, a2); pswap(a1, a3);
      bp[blk * 8 + 0] = a0; bp[blk * 8 + 1] = a1;
      bp[blk * 8 + 2] = a2; bp[blk * 8 + 3] = a3;
      unsigned int b0 = cvt_pk_bf16(s[8],  s[9]);
      unsigned int b1 = cvt_pk_bf16(s[10], s[11]);
      unsigned int b2 = cvt_pk_bf16(s[12], s[13]);
      unsigned int b3 = cvt_pk_bf16(s[14], s[15]);
      pswap(b0, b2); pswap(b1, b3);
      bp[blk * 8 + 4] = b0; bp[blk * 8 + 5] = b1;
      bp[blk * 8 + 6] = b2; bp[blk * 8 + 7] = b3;
    }

    __builtin_amdgcn_s_setprio(1);
#pragma unroll
    for (int ss = 0; ss < 4; ++ss) {
      uint4 u = {bp[ss * 4], bp[ss * 4 + 1], bp[ss * 4 + 2], bp[ss * 4 + 3]};
      s16x8 pb = __builtin_bit_cast(s16x8, u);
      int cx = (ss * 32 + hi * 16) ^ swz;
      s16x8 v0 = *(const s16x8*)(sV[cur] + ql * 128 + cx);
      s16x8 v1 = *(const s16x8*)(sV[cur] + (32 + ql) * 128 + cx);
      oa0 = __builtin_amdgcn_mfma_f32_32x32x16_bf16(v0, pb, oa0, 0, 0, 0);
      oa1 = __builtin_amdgcn_mfma_f32_32x32x16_bf16(v1, pb, oa1, 0, 0, 0);
    }
    __builtin_amdgcn_s_setprio(0);

    ++cur; if (cur == 3) cur = 0;
  }
#undef STAGE

  l_run += __shfl_xor(l_run, 32);
  float inv = 1.f / l_run;
  const int b = bh >> 4, h = bh & 15;
  const int q = q0 + 32 * w + ql;
  unsigned short* crow = Ctx + ((size_t)(b * 2048 + q)) * 1024 + h * 64;
#pragma unroll
  for (int dblk = 0; dblk < 2; ++dblk) {
    const f32x16& oa = dblk ? oa1 : oa0;
#pragma unroll
    for (int grp = 0; grp < 4; ++grp) {
      ushort4 st;
      st.x = f2bf(oa[4 * grp + 0] * inv);
      st.y = f2bf(oa[4 * grp + 1] * inv);
      st.z = f2bf(oa[4 * grp + 2] * inv);
      st.w = f2bf(oa[4 * grp + 3] * inv);
      *(ushort4*)(crow + dblk * 32 + 8 * grp + 4 * hi) = st;
    }
  }
}

extern "C" void kernel_launch(void* const* d_in, const int* in_sizes, int n_in,
                              void* d_out, int out_size, void* d_ws, size_t ws_size,
                              hipStream_t stream) {
  const float* hidden = (const float*)d_in[0];   // (4,2048,1024) f32
  const int*   pos    = (const int*)d_in[1];     // (4,2048) i32
  const float* wqkv   = (const float*)d_in[2];   // (3072,1024) f32
  const float* wo     = (const float*)d_in[3];   // (1024,1024) f32

  char* ws = (char*)d_ws;
  unsigned short* hbf  = (unsigned short*)(ws);                 // 16,777,216 B
  unsigned short* wqbf = (unsigned short*)(ws + 16777216);      //  6,291,456
  unsigned short* wobf = (unsigned short*)(ws + 23068672);      //  2,097,152
  unsigned short* Qr   = (unsigned short*)(ws + 41943040);      // 16,777,216
  unsigned short* Kr   = (unsigned short*)(ws + 58720256);      // 16,777,216
  unsigned short* Vt   = (unsigned short*)(ws + 75497472);      // 16,777,216
  unsigned short* ctx  = (unsigned short*)(ws + 92274688);      // 16,777,216
  float*          ctab = (float*)(ws + 109051904);              //  1,048,576
  float*          stab = (float*)(ws + 110100480);              //  1,048,576
  // total: 111,149,056 B

  cvt_rope_kernel<<<13312, 256, 0, stream>>>(hidden, wqkv, wo, pos,
                                             hbf, wqbf, wobf, ctab, stab);

  dim3 gq(32, 24);
  gemm2_kernel<2><<<gq, 512, 98304, stream>>>(hbf, wqbf, nullptr, 3072, 1024,
                                              ctab, stab, Qr, Kr, Vt);

  dim3 ga(8, 64);
  attn_kernel<<<ga, 512, 0, stream>>>(Qr, Kr, Vt, ctx);

  dim3 go(32, 8);
  gemm2_kernel<1><<<go, 512, 98304, stream>>>(ctx, wobf, d_out, 1024, 1024,
                                              nullptr, nullptr, nullptr, nullptr, nullptr);
}

// Round 15
// 183.056 us; speedup vs baseline: 1.8707x; 1.0102x over previous
//
#include <hip/hip_runtime.h>
#include <hip/hip_bf16.h>

// ModernBertAttention: B=4 S=2048 H=1024 NH=16 HD=64, rope theta=160000, f32 in/out.
// R15: GEMM geometry resized to 256x64 tile / 80KB LDS -> 2 blocks/CU (16 waves/CU,
//      2x R14's residency) with the same counted-vmcnt(2) cross-barrier pipeline.
//      One head per block => simpler rope/V epilogues. attn frozen (83.5us).

#define GLOBAL_AS __attribute__((address_space(1)))
#define LDS_AS    __attribute__((address_space(3)))

using f32x4  = __attribute__((ext_vector_type(4))) float;
using f32x16 = __attribute__((ext_vector_type(16))) float;
using s16x8  = __attribute__((ext_vector_type(8))) short;

__device__ __forceinline__ void gld_lds16(const void* g, void* l) {
  __builtin_amdgcn_global_load_lds((const GLOBAL_AS void*)g, (LDS_AS void*)l, 16, 0, 0);
}

__device__ __forceinline__ unsigned short f2bf(float f) {
  unsigned int u = __float_as_uint(f);
  u = (u + 0x7fffu + ((u >> 16) & 1u)) >> 16;   // RNE
  return (unsigned short)u;
}
__device__ __forceinline__ unsigned int cvt_pk_bf16(float lo, float hi) {
  unsigned int r;
  asm("v_cvt_pk_bf16_f32 %0, %1, %2" : "=v"(r) : "v"(lo), "v"(hi));
  return r;
}
__device__ __forceinline__ void pswap(unsigned int& a, unsigned int& b) {
  asm("v_permlane32_swap_b32 %0, %1" : "+v"(a), "+v"(b));
}

// ---------- merged f32->bf16 convert + rope table (blocks >= 12288) ----------
__global__ __launch_bounds__(256) void cvt_rope_kernel(const float* __restrict__ h,
                                                       const float* __restrict__ wq,
                                                       const float* __restrict__ wo,
                                                       const int* __restrict__ pos,
                                                       unsigned short* __restrict__ hb,
                                                       unsigned short* __restrict__ wqb,
                                                       unsigned short* __restrict__ wob,
                                                       float* __restrict__ ctab,
                                                       float* __restrict__ stab) {
  int b = blockIdx.x;
  if (b >= 12288) {   // rope table: B*S*32 entries
    int idx = (b - 12288) * 256 + threadIdx.x;
    int d = idx & 31;
    int bs = idx >> 5;
    float p = (float)pos[bs];
    float inv = exp2f(-(float)d * 0.5402410118609203f);  // theta^(-d/32)
    float f = p * inv;
    ctab[idx] = cosf(f);
    stab[idx] = sinf(f);
    return;
  }
  const float* src; unsigned short* dst; int i;
  if (b < 8192)       { src = h;  dst = hb;  i = b * 256 + threadIdx.x; }
  else if (b < 11264) { src = wq; dst = wqb; i = (b - 8192) * 256 + threadIdx.x; }
  else                { src = wo; dst = wob; i = (b - 11264) * 256 + threadIdx.x; }
  float4 v = ((const float4*)src)[i];
  ushort4 o;
  o.x = f2bf(v.x); o.y = f2bf(v.y); o.z = f2bf(v.z); o.w = f2bf(v.w);
  ((ushort4*)dst)[i] = o;
}

// ------- GEMM C[m,n]=sum_k A[m,k]B[n,k]: 256x64 tile, 8 waves (32 rows each), BK=64 -------
// 80KB dbuf LDS (2 blocks/CU). Counted vmcnt(2): next tile's A-first-half stays in
// flight across every boundary barrier. Loads/tile: A=4/thread (2 halves), B=1.
// MODE 1: f32 C. MODE 2: QKV epilogue, 1 head/block (rope -> Qr/Kr; V -> Vt transpose).
template<int MODE>
__global__ __launch_bounds__(512, 4) void gemm2_kernel(const unsigned short* __restrict__ A,
                                                       const unsigned short* __restrict__ Bm,
                                                       void* __restrict__ C, int N, int K,
                                                       const float* __restrict__ ctab,
                                                       const float* __restrict__ stab,
                                                       unsigned short* __restrict__ Qr,
                                                       unsigned short* __restrict__ Kr,
                                                       unsigned short* __restrict__ Vt) {
  extern __shared__ char lds[];   // 81920 B: 2 dbuf x (A 32KB + B 8KB)
  const int tid  = threadIdx.x;
  const int lane = tid & 63, w = tid >> 6;   // 8 waves, wave rows w*32..w*32+31
  const int g = lane >> 4, c = lane & 15;
  const int m0 = blockIdx.x * 256, n0 = blockIdx.y * 64;
  const char* Ab = (const char*)A;
  const char* Bb = (const char*)Bm;
  const int NKT = K >> 6;                    // 16

  // A-half hh (128 rows x 128B = 16KB, 2 loads/thread) of K-tile kt
#define STAGE_A(kt, hh)                                                           \
  {                                                                               \
    _Pragma("unroll")                                                             \
    for (int L = 0; L < 2; ++L) {                                                 \
      int o = tid * 16 + L * 8192;                                                \
      int row = o >> 7;                                                           \
      int gcol = (o & 127) ^ ((row & 7) << 4);                                    \
      gld_lds16(Ab + ((size_t)(m0 + (hh) * 128 + row) * K + (kt) * 64) * 2 + gcol,\
                lds + ((kt) & 1) * 40960 + (hh) * 16384 + o);                     \
    }                                                                             \
  }
  // B tile (64 rows x 128B = 8KB, 1 load/thread)
#define STAGE_B(kt)                                                               \
  {                                                                               \
    int o = tid * 16;                                                             \
    int row = o >> 7;                                                             \
    int gcol = (o & 127) ^ ((row & 7) << 4);                                      \
    gld_lds16(Bb + ((size_t)(n0 + row) * K + (kt) * 64) * 2 + gcol,               \
              lds + ((kt) & 1) * 40960 + 32768 + o);                              \
  }

  // prologue: kt0 complete (5), then kt1 A-half0 (2)
  STAGE_A(0, 0); STAGE_A(0, 1); STAGE_B(0);
  __builtin_amdgcn_sched_barrier(0);
  STAGE_A(1, 0);
  __builtin_amdgcn_sched_barrier(0);

  f32x4 acc[2][4] = {};
  for (int kt = 0; kt < NKT; ++kt) {
    // boundary: drain kt's 5 loads (oldest), leave kt+1's A-half0 (2) in flight
    if (kt == NKT - 1) asm volatile("s_waitcnt vmcnt(0)" ::: "memory");
    else               asm volatile("s_waitcnt vmcnt(2)" ::: "memory");
    __builtin_amdgcn_sched_barrier(0);
    __builtin_amdgcn_s_barrier();
    __builtin_amdgcn_sched_barrier(0);

    const char* baseA = lds + (kt & 1) * 40960;
    const char* baseB = baseA + 32768;

    s16x8 af[2][2], bf[4][2];
#pragma unroll
    for (int i = 0; i < 2; ++i) {
      int row = w * 32 + 16 * i + c;
#pragma unroll
      for (int ks = 0; ks < 2; ++ks)
        af[i][ks] = *(const s16x8*)(baseA + ((row * 128 + ks * 64 + g * 16) ^ ((row & 7) << 4)));
    }
#pragma unroll
    for (int j = 0; j < 4; ++j) {
      int row = 16 * j + c;
#pragma unroll
      for (int ks = 0; ks < 2; ++ks)
        bf[j][ks] = *(const s16x8*)(baseB + ((row * 128 + ks * 64 + g * 16) ^ ((row & 7) << 4)));
    }

    if (kt + 1 < NKT) {   // stage kt+1's A-half1 + B (other dbuf; no race)
      STAGE_A(kt + 1, 1);
      STAGE_B(kt + 1);
    }
    __builtin_amdgcn_sched_barrier(0);

    __builtin_amdgcn_s_setprio(1);
#pragma unroll
    for (int ks = 0; ks < 2; ++ks)
#pragma unroll
      for (int i = 0; i < 2; ++i)
#pragma unroll
        for (int j = 0; j < 4; ++j)
          acc[i][j] = __builtin_amdgcn_mfma_f32_16x16x32_bf16(af[i][ks], bf[j][ks], acc[i][j], 0, 0, 0);
    __builtin_amdgcn_s_setprio(0);

    __builtin_amdgcn_sched_barrier(0);
    __builtin_amdgcn_s_barrier();   // all waves done reading dbuf[kt&1]
    __builtin_amdgcn_sched_barrier(0);
    if (kt + 2 < NKT) {             // restage freed buffer: kt+2's A-half0
      STAGE_A(kt + 2, 0);
      __builtin_amdgcn_sched_barrier(0);
    }
  }
#undef STAGE_A
#undef STAGE_B

  if (MODE == 1) {
#pragma unroll
    for (int i = 0; i < 2; ++i)
#pragma unroll
      for (int j = 0; j < 4; ++j)
#pragma unroll
        for (int r = 0; r < 4; ++r) {
          int m = m0 + w * 32 + 16 * i + 4 * g + r;
          int n = n0 + 16 * j + c;
          ((float*)C)[(size_t)m * N + n] = acc[i][j][r];
        }
  } else {
    const int t = blockIdx.y;   // 0..15 Q head t, 16..31 K head t-16, 32..47 V head t-32
    if (t < 32) {
      unsigned short* dstb = (t < 16) ? Qr : Kr;
      const float qs = (t < 16) ? 0.18033688011112042f : 1.0f;  // SCALE*log2(e) on Q
      const int h = t & 15;
#pragma unroll
      for (int i = 0; i < 2; ++i)
#pragma unroll
        for (int r = 0; r < 4; ++r) {
          int m = m0 + w * 32 + 16 * i + 4 * g + r;
          int b = m >> 11, s = m & 2047;
          unsigned short* drow = dstb + ((size_t)(b * 16 + h) * 2048 + s) * 64;
#pragma unroll
          for (int j = 0; j < 2; ++j) {
            int d = 16 * j + c;
            float co = ctab[(size_t)m * 32 + d];
            float si = stab[(size_t)m * 32 + d];
            float x1 = acc[i][j][r], x2 = acc[i][j + 2][r];
            drow[d]      = f2bf((x1 * co - x2 * si) * qs);
            drow[d + 32] = f2bf((x2 * co + x1 * si) * qs);
          }
        }
    } else {
      // V epilogue: head h = t-32; transpose 256s x 64d via LDS, write Vt directly.
      // tile uses lds[0..36864) = dbuf0; final K-tile (kt=15, odd) read dbuf1 -> no overlap.
      unsigned short (*tile)[72] = (unsigned short (*)[72])lds;
      const int bb = m0 >> 11, sb = m0 & 2047;
      const int h = t - 32;
      // last loop iteration ended with s_barrier; dbuf0's final reads were kt=14 (synced)
#pragma unroll
      for (int i = 0; i < 2; ++i)
#pragma unroll
        for (int j = 0; j < 4; ++j)
#pragma unroll
          for (int r = 0; r < 4; ++r)
            tile[w * 32 + 16 * i + 4 * g + r][16 * j + c] = f2bf(acc[i][j][r]);
      __syncthreads();
      int d = tid >> 3, p = tid & 7;             // d 0..63, p = s-chunk (32 s each)
      alignas(16) unsigned short vv[32];
#pragma unroll
      for (int i2 = 0; i2 < 32; ++i2) vv[i2] = tile[p * 32 + i2][d];
      unsigned short* dst = Vt + ((size_t)(bb * 16 + h) * 64 + d) * 2048 + sb + p * 32;
#pragma unroll
      for (int q4 = 0; q4 < 4; ++q4)
        *(uint4*)(dst + 8 * q4) = ((const uint4*)vv)[q4];
    }
  }
}

// ---------------- flash attention: 256 q/block, 8 waves x 32 q, 32x32x16 MFMA ----------------
// (frozen at R11/R13) Triple-buffered K/V; counted vmcnt(2); one raw barrier/iter; in-reg P.
__global__ __launch_bounds__(512) void attn_kernel(const unsigned short* __restrict__ Q,
                                                   const unsigned short* __restrict__ Kr,
                                                   const unsigned short* __restrict__ Vt,
                                                   unsigned short* __restrict__ Ctx) {
  __shared__ char sK[3][8192];   // 64 kv rows x 128B, swizzle (row&7)<<4
  __shared__ char sV[3][8192];   // 64 d rows x 128B (V^T tile)
  const int tid  = threadIdx.x;
  const int lane = tid & 63, w = tid >> 6;       // w in 0..7
  const int hi = lane >> 5, ql = lane & 31;
  const int swz = (ql & 7) << 4;
  int lin = blockIdx.x + 8 * blockIdx.y;         // grid (8, 64) = 512 blocks
  int eff = (lin & 7) * 64 + (lin >> 3);
  const int bh = eff >> 3;                       // 0..63
  const int q0 = (eff & 7) * 256;
  const char* kh = (const char*)(Kr + (size_t)bh * 2048 * 64);
  const char* vh = (const char*)(Vt + (size_t)bh * 64 * 2048);

  s16x8 qf[4];
  {
    const char* qrow = (const char*)Q + ((size_t)bh * 2048 + q0 + 32 * w + ql) * 128;
#pragma unroll
    for (int t = 0; t < 4; ++t) qf[t] = *(const s16x8*)(qrow + t * 32 + hi * 16);
  }
  __builtin_amdgcn_sched_barrier(0);   // qf loads issued before any STAGE

#define STAGE(t, b)                                                              \
  {                                                                              \
    int o = tid * 16;                                                            \
    int l = o ^ (((o >> 7) & 7) << 4);                                           \
    gld_lds16(kh + (size_t)(t) * 8192 + l, sK[b] + o);                           \
    gld_lds16(vh + (size_t)(o >> 7) * 4096 + (t) * 128 + (l & 127), sV[b] + o);  \
  }

  STAGE(0, 0);
  __builtin_amdgcn_sched_barrier(0);
  STAGE(1, 1);
  __builtin_amdgcn_sched_barrier(0);

  float l_run = 0.f;
  f32x16 oa0 = {}, oa1 = {};   // D[d][q]: d 0-31, d 32-63
  int cur = 0;

  for (int it = 0; it < 32; ++it) {
    if (it == 0 || it == 31) asm volatile("s_waitcnt vmcnt(0)" ::: "memory");
    else                     asm volatile("s_waitcnt vmcnt(2)" ::: "memory");
    __builtin_amdgcn_sched_barrier(0);
    __builtin_amdgcn_s_barrier();
    __builtin_amdgcn_sched_barrier(0);

    if (it + 2 < 32) {
      int sb = cur + 2; if (sb >= 3) sb -= 3;
      STAGE(it + 2, sb);
    }
    __builtin_amdgcn_sched_barrier(0);

    f32x16 sc0 = {}, sc1 = {};
    __builtin_amdgcn_s_setprio(1);
#pragma unroll
    for (int t = 0; t < 4; ++t) {
      int cx = (t * 32 + hi * 16) ^ swz;
      s16x8 k0 = *(const s16x8*)(sK[cur] + ql * 128 + cx);
      s16x8 k1 = *(const s16x8*)(sK[cur] + (32 + ql) * 128 + cx);
      sc0 = __builtin_amdgcn_mfma_f32_32x32x16_bf16(k0, qf[t], sc0, 0, 0, 0);
      sc1 = __builtin_amdgcn_mfma_f32_32x32x16_bf16(k1, qf[t], sc1, 0, 0, 0);
    }
    __builtin_amdgcn_s_setprio(0);

    float rs = 0.f;
#pragma unroll
    for (int r = 0; r < 16; ++r) { sc0[r] = __builtin_amdgcn_exp2f(sc0[r]); rs += sc0[r]; }
#pragma unroll
    for (int r = 0; r < 16; ++r) { sc1[r] = __builtin_amdgcn_exp2f(sc1[r]); rs += sc1[r]; }
    l_run += rs;

    unsigned int bp[16];
#pragma unroll
    for (int blk = 0; blk < 2; ++blk) {
      const f32x16& s = blk ? sc1 : sc0;
      unsigned int a0 = cvt_pk_bf16(s[0],  s[1]);
      unsigned int a1 = cvt_pk_bf16(s[2],  s[3]);
      unsigned int a2 = cvt_pk_bf16(s[4],  s[5]);
      unsigned int a3 = cvt_pk_bf16(s[6],  s[7]);
      pswap(a0, a2); pswap(a1, a3);
      bp[blk * 8 + 0] = a0; bp[blk * 8 + 1] = a1;
      bp[blk * 8 + 2] = a2; bp[blk * 8 + 3] = a3;
      unsigned int b0 = cvt_pk_bf16(s[8],  s[9]);
      unsigned int b1 = cvt_pk_bf16(s[10], s[11]);
      unsigned int b2 = cvt_pk_bf16(s[12], s[13]);
      unsigned int b3 = cvt_pk_bf16(s[14], s[15]);
      pswap(b0, b2); pswap(b1, b3);
      bp[blk * 8 + 4] = b0; bp[blk * 8 + 5] = b1;
      bp[blk * 8 + 6] = b2; bp[blk * 8 + 7] = b3;
    }

    __builtin_amdgcn_s_setprio(1);
#pragma unroll
    for (int ss = 0; ss < 4; ++ss) {
      uint4 u = {bp[ss * 4], bp[ss * 4 + 1], bp[ss * 4 + 2], bp[ss * 4 + 3]};
      s16x8 pb = __builtin_bit_cast(s16x8, u);
      int cx = (ss * 32 + hi * 16) ^ swz;
      s16x8 v0 = *(const s16x8*)(sV[cur] + ql * 128 + cx);
      s16x8 v1 = *(const s16x8*)(sV[cur] + (32 + ql) * 128 + cx);
      oa0 = __builtin_amdgcn_mfma_f32_32x32x16_bf16(v0, pb, oa0, 0, 0, 0);
      oa1 = __builtin_amdgcn_mfma_f32_32x32x16_bf16(v1, pb, oa1, 0, 0, 0);
    }
    __builtin_amdgcn_s_setprio(0);

    ++cur; if (cur == 3) cur = 0;
  }
#undef STAGE

  l_run += __shfl_xor(l_run, 32);
  float inv = 1.f / l_run;
  const int b = bh >> 4, h = bh & 15;
  const int q = q0 + 32 * w + ql;
  unsigned short* crow = Ctx + ((size_t)(b * 2048 + q)) * 1024 + h * 64;
#pragma unroll
  for (int dblk = 0; dblk < 2; ++dblk) {
    const f32x16& oa = dblk ? oa1 : oa0;
#pragma unroll
    for (int grp = 0; grp < 4; ++grp) {
      ushort4 st;
      st.x = f2bf(oa[4 * grp + 0] * inv);
      st.y = f2bf(oa[4 * grp + 1] * inv);
      st.z = f2bf(oa[4 * grp + 2] * inv);
      st.w = f2bf(oa[4 * grp + 3] * inv);
      *(ushort4*)(crow + dblk * 32 + 8 * grp + 4 * hi) = st;
    }
  }
}

extern "C" void kernel_launch(void* const* d_in, const int* in_sizes, int n_in,
                              void* d_out, int out_size, void* d_ws, size_t ws_size,
                              hipStream_t stream) {
  const float* hidden = (const float*)d_in[0];   // (4,2048,1024) f32
  const int*   pos    = (const int*)d_in[1];     // (4,2048) i32
  const float* wqkv   = (const float*)d_in[2];   // (3072,1024) f32
  const float* wo     = (const float*)d_in[3];   // (1024,1024) f32

  char* ws = (char*)d_ws;
  unsigned short* hbf  = (unsigned short*)(ws);                 // 16,777,216 B
  unsigned short* wqbf = (unsigned short*)(ws + 16777216);      //  6,291,456
  unsigned short* wobf = (unsigned short*)(ws + 23068672);      //  2,097,152
  unsigned short* Qr   = (unsigned short*)(ws + 41943040);      // 16,777,216
  unsigned short* Kr   = (unsigned short*)(ws + 58720256);      // 16,777,216
  unsigned short* Vt   = (unsigned short*)(ws + 75497472);      // 16,777,216
  unsigned short* ctx  = (unsigned short*)(ws + 92274688);      // 16,777,216
  float*          ctab = (float*)(ws + 109051904);              //  1,048,576
  float*          stab = (float*)(ws + 110100480);              //  1,048,576
  // total: 111,149,056 B

  cvt_rope_kernel<<<13312, 256, 0, stream>>>(hidden, wqkv, wo, pos,
                                             hbf, wqbf, wobf, ctab, stab);

  dim3 gq(32, 48);
  gemm2_kernel<2><<<gq, 512, 81920, stream>>>(hbf, wqbf, nullptr, 3072, 1024,
                                              ctab, stab, Qr, Kr, Vt);

  dim3 ga(8, 64);
  attn_kernel<<<ga, 512, 0, stream>>>(Qr, Kr, Vt, ctx);

  dim3 go(32, 16);
  gemm2_kernel<1><<<go, 512, 81920, stream>>>(ctx, wobf, d_out, 1024, 1024,
                                              nullptr, nullptr, nullptr, nullptr, nullptr);
}

// Round 16
// 179.238 us; speedup vs baseline: 1.9105x; 1.0213x over previous
//
#include <hip/hip_runtime.h>
#include <hip/hip_bf16.h>

// ModernBertAttention: B=4 S=2048 H=1024 NH=16 HD=64, rope theta=160000, f32 in/out.
// R16: GEMM = 256x64 block, 4 waves x 64x64 wave tile (halves LDS reads per MFMA:
//      16 ds_read_b128 : 32 MFMA), 80KB LDS -> 2 blocks/CU, counted vmcnt(4).
//      attn frozen (83.5us). cvt_rope unchanged.

#define GLOBAL_AS __attribute__((address_space(1)))
#define LDS_AS    __attribute__((address_space(3)))

using f32x4  = __attribute__((ext_vector_type(4))) float;
using f32x16 = __attribute__((ext_vector_type(16))) float;
using s16x8  = __attribute__((ext_vector_type(8))) short;

__device__ __forceinline__ void gld_lds16(const void* g, void* l) {
  __builtin_amdgcn_global_load_lds((const GLOBAL_AS void*)g, (LDS_AS void*)l, 16, 0, 0);
}

__device__ __forceinline__ unsigned short f2bf(float f) {
  unsigned int u = __float_as_uint(f);
  u = (u + 0x7fffu + ((u >> 16) & 1u)) >> 16;   // RNE
  return (unsigned short)u;
}
__device__ __forceinline__ unsigned int cvt_pk_bf16(float lo, float hi) {
  unsigned int r;
  asm("v_cvt_pk_bf16_f32 %0, %1, %2" : "=v"(r) : "v"(lo), "v"(hi));
  return r;
}
__device__ __forceinline__ void pswap(unsigned int& a, unsigned int& b) {
  asm("v_permlane32_swap_b32 %0, %1" : "+v"(a), "+v"(b));
}

// ---------- merged f32->bf16 convert + rope table (blocks >= 12288) ----------
__global__ __launch_bounds__(256) void cvt_rope_kernel(const float* __restrict__ h,
                                                       const float* __restrict__ wq,
                                                       const float* __restrict__ wo,
                                                       const int* __restrict__ pos,
                                                       unsigned short* __restrict__ hb,
                                                       unsigned short* __restrict__ wqb,
                                                       unsigned short* __restrict__ wob,
                                                       float* __restrict__ ctab,
                                                       float* __restrict__ stab) {
  int b = blockIdx.x;
  if (b >= 12288) {   // rope table: B*S*32 entries
    int idx = (b - 12288) * 256 + threadIdx.x;
    int d = idx & 31;
    int bs = idx >> 5;
    float p = (float)pos[bs];
    float inv = exp2f(-(float)d * 0.5402410118609203f);  // theta^(-d/32)
    float f = p * inv;
    ctab[idx] = cosf(f);
    stab[idx] = sinf(f);
    return;
  }
  const float* src; unsigned short* dst; int i;
  if (b < 8192)       { src = h;  dst = hb;  i = b * 256 + threadIdx.x; }
  else if (b < 11264) { src = wq; dst = wqb; i = (b - 8192) * 256 + threadIdx.x; }
  else                { src = wo; dst = wob; i = (b - 11264) * 256 + threadIdx.x; }
  float4 v = ((const float4*)src)[i];
  ushort4 o;
  o.x = f2bf(v.x); o.y = f2bf(v.y); o.z = f2bf(v.z); o.w = f2bf(v.w);
  ((ushort4*)dst)[i] = o;
}

// ---- GEMM C[m,n]=sum_k A[m,k]B[n,k]: 256x64 block, 4 waves (64x64 wave tile), BK=64 ----
// 80KB dbuf LDS (2 blocks/CU). 16 ds_read_b128 : 32 MFMA per wave per K-tile.
// Counted vmcnt(4): next tile's A-half0 (4 loads) stays in flight across barriers.
// MODE 1: f32 C. MODE 2: QKV epilogue, 1 head/block (rope -> Qr/Kr; V -> Vt transpose).
template<int MODE>
__global__ __launch_bounds__(256, 2) void gemm3_kernel(const unsigned short* __restrict__ A,
                                                       const unsigned short* __restrict__ Bm,
                                                       void* __restrict__ C, int N, int K,
                                                       const float* __restrict__ ctab,
                                                       const float* __restrict__ stab,
                                                       unsigned short* __restrict__ Qr,
                                                       unsigned short* __restrict__ Kr,
                                                       unsigned short* __restrict__ Vt) {
  extern __shared__ char lds[];   // 81920 B: 2 dbuf x (A 32KB + B 8KB)
  const int tid  = threadIdx.x;
  const int lane = tid & 63, w = tid >> 6;   // 4 waves, wave rows w*64..w*64+63
  const int g = lane >> 4, c = lane & 15;
  const int m0 = blockIdx.x * 256, n0 = blockIdx.y * 64;
  const char* Ab = (const char*)A;
  const char* Bb = (const char*)Bm;
  const int NKT = K >> 6;                    // 16

  // A-half hh (128 rows x 128B = 16KB, 4 loads/thread) of K-tile kt
#define STAGE_A(kt, hh)                                                           \
  {                                                                               \
    _Pragma("unroll")                                                             \
    for (int L = 0; L < 4; ++L) {                                                 \
      int o = tid * 16 + L * 4096;                                                \
      int row = o >> 7;                                                           \
      int gcol = (o & 127) ^ ((row & 7) << 4);                                    \
      gld_lds16(Ab + ((size_t)(m0 + (hh) * 128 + row) * K + (kt) * 64) * 2 + gcol,\
                lds + ((kt) & 1) * 40960 + (hh) * 16384 + o);                     \
    }                                                                             \
  }
  // B tile (64 rows x 128B = 8KB, 2 loads/thread)
#define STAGE_B(kt)                                                               \
  {                                                                               \
    _Pragma("unroll")                                                             \
    for (int L = 0; L < 2; ++L) {                                                 \
      int o = tid * 16 + L * 4096;                                                \
      int row = o >> 7;                                                           \
      int gcol = (o & 127) ^ ((row & 7) << 4);                                    \
      gld_lds16(Bb + ((size_t)(n0 + row) * K + (kt) * 64) * 2 + gcol,             \
                lds + ((kt) & 1) * 40960 + 32768 + o);                            \
    }                                                                             \
  }

  // prologue: kt0 complete (10 loads/thread), then kt1 A-half0 (4)
  STAGE_A(0, 0); STAGE_A(0, 1); STAGE_B(0);
  __builtin_amdgcn_sched_barrier(0);
  STAGE_A(1, 0);
  __builtin_amdgcn_sched_barrier(0);

  f32x4 acc[4][4] = {};
  for (int kt = 0; kt < NKT; ++kt) {
    // boundary: drain kt's 10 loads (oldest), leave kt+1's A-half0 (4) in flight
    if (kt == 0 || kt == NKT - 1) asm volatile("s_waitcnt vmcnt(0)" ::: "memory");
    else                          asm volatile("s_waitcnt vmcnt(4)" ::: "memory");
    __builtin_amdgcn_sched_barrier(0);
    __builtin_amdgcn_s_barrier();
    __builtin_amdgcn_sched_barrier(0);

    const char* baseA = lds + (kt & 1) * 40960;
    const char* baseB = baseA + 32768;

    s16x8 af[4][2], bf[4][2];
#pragma unroll
    for (int i = 0; i < 4; ++i) {
      int row = w * 64 + 16 * i + c;
#pragma unroll
      for (int ks = 0; ks < 2; ++ks)
        af[i][ks] = *(const s16x8*)(baseA + ((row * 128 + ks * 64 + g * 16) ^ ((row & 7) << 4)));
    }
#pragma unroll
    for (int j = 0; j < 4; ++j) {
      int row = 16 * j + c;
#pragma unroll
      for (int ks = 0; ks < 2; ++ks)
        bf[j][ks] = *(const s16x8*)(baseB + ((row * 128 + ks * 64 + g * 16) ^ ((row & 7) << 4)));
    }

    if (kt + 1 < NKT) {   // stage kt+1's A-half1 + B (other dbuf; no race)
      STAGE_A(kt + 1, 1);
      STAGE_B(kt + 1);
    }
    __builtin_amdgcn_sched_barrier(0);

    __builtin_amdgcn_s_setprio(1);
#pragma unroll
    for (int ks = 0; ks < 2; ++ks)
#pragma unroll
      for (int i = 0; i < 4; ++i)
#pragma unroll
        for (int j = 0; j < 4; ++j)
          acc[i][j] = __builtin_amdgcn_mfma_f32_16x16x32_bf16(af[i][ks], bf[j][ks], acc[i][j], 0, 0, 0);
    __builtin_amdgcn_s_setprio(0);

    __builtin_amdgcn_sched_barrier(0);
    __builtin_amdgcn_s_barrier();   // all waves done reading dbuf[kt&1]
    __builtin_amdgcn_sched_barrier(0);
    if (kt + 2 < NKT) {             // restage freed buffer: kt+2's A-half0
      STAGE_A(kt + 2, 0);
      __builtin_amdgcn_sched_barrier(0);
    }
  }
#undef STAGE_A
#undef STAGE_B

  if (MODE == 1) {
#pragma unroll
    for (int i = 0; i < 4; ++i)
#pragma unroll
      for (int j = 0; j < 4; ++j)
#pragma unroll
        for (int r = 0; r < 4; ++r) {
          int m = m0 + w * 64 + 16 * i + 4 * g + r;
          int n = n0 + 16 * j + c;
          ((float*)C)[(size_t)m * N + n] = acc[i][j][r];
        }
  } else {
    const int t = blockIdx.y;   // 0..15 Q head t, 16..31 K head t-16, 32..47 V head t-32
    if (t < 32) {
      unsigned short* dstb = (t < 16) ? Qr : Kr;
      const float qs = (t < 16) ? 0.18033688011112042f : 1.0f;  // SCALE*log2(e) on Q
      const int h = t & 15;
#pragma unroll
      for (int i = 0; i < 4; ++i)
#pragma unroll
        for (int r = 0; r < 4; ++r) {
          int m = m0 + w * 64 + 16 * i + 4 * g + r;
          int b = m >> 11, s = m & 2047;
          unsigned short* drow = dstb + ((size_t)(b * 16 + h) * 2048 + s) * 64;
#pragma unroll
          for (int j = 0; j < 2; ++j) {
            int d = 16 * j + c;
            float co = ctab[(size_t)m * 32 + d];
            float si = stab[(size_t)m * 32 + d];
            float x1 = acc[i][j][r], x2 = acc[i][j + 2][r];
            drow[d]      = f2bf((x1 * co - x2 * si) * qs);
            drow[d + 32] = f2bf((x2 * co + x1 * si) * qs);
          }
        }
    } else {
      // V epilogue: head h = t-32; transpose 256s x 64d via LDS, write Vt directly.
      // tile uses lds[0..36864) = dbuf0; final K-tile (kt=15, odd) read dbuf1 -> no overlap.
      unsigned short (*tile)[72] = (unsigned short (*)[72])lds;
      const int bb = m0 >> 11, sb = m0 & 2047;
      const int h = t - 32;
      // loop ended with a block-wide s_barrier; dbuf0's final reads were kt=14 (synced)
#pragma unroll
      for (int i = 0; i < 4; ++i)
#pragma unroll
        for (int j = 0; j < 4; ++j)
#pragma unroll
          for (int r = 0; r < 4; ++r)
            tile[w * 64 + 16 * i + 4 * g + r][16 * j + c] = f2bf(acc[i][j][r]);
      __syncthreads();
      int d = tid >> 2, p = tid & 3;             // d 0..63, p = s-chunk (64 s each)
      unsigned short* dst = Vt + ((size_t)(bb * 16 + h) * 64 + d) * 2048 + sb + p * 64;
#pragma unroll
      for (int q8 = 0; q8 < 8; ++q8) {
        alignas(16) unsigned short tmp[8];
#pragma unroll
        for (int i2 = 0; i2 < 8; ++i2) tmp[i2] = tile[p * 64 + q8 * 8 + i2][d];
        *(uint4*)(dst + q8 * 8) = *(const uint4*)tmp;
      }
    }
  }
}

// ---------------- flash attention: 256 q/block, 8 waves x 32 q, 32x32x16 MFMA ----------------
// (frozen at R11/R13) Triple-buffered K/V; counted vmcnt(2); one raw barrier/iter; in-reg P.
__global__ __launch_bounds__(512) void attn_kernel(const unsigned short* __restrict__ Q,
                                                   const unsigned short* __restrict__ Kr,
                                                   const unsigned short* __restrict__ Vt,
                                                   unsigned short* __restrict__ Ctx) {
  __shared__ char sK[3][8192];   // 64 kv rows x 128B, swizzle (row&7)<<4
  __shared__ char sV[3][8192];   // 64 d rows x 128B (V^T tile)
  const int tid  = threadIdx.x;
  const int lane = tid & 63, w = tid >> 6;       // w in 0..7
  const int hi = lane >> 5, ql = lane & 31;
  const int swz = (ql & 7) << 4;
  int lin = blockIdx.x + 8 * blockIdx.y;         // grid (8, 64) = 512 blocks
  int eff = (lin & 7) * 64 + (lin >> 3);
  const int bh = eff >> 3;                       // 0..63
  const int q0 = (eff & 7) * 256;
  const char* kh = (const char*)(Kr + (size_t)bh * 2048 * 64);
  const char* vh = (const char*)(Vt + (size_t)bh * 64 * 2048);

  s16x8 qf[4];
  {
    const char* qrow = (const char*)Q + ((size_t)bh * 2048 + q0 + 32 * w + ql) * 128;
#pragma unroll
    for (int t = 0; t < 4; ++t) qf[t] = *(const s16x8*)(qrow + t * 32 + hi * 16);
  }
  __builtin_amdgcn_sched_barrier(0);   // qf loads issued before any STAGE

#define STAGE(t, b)                                                              \
  {                                                                              \
    int o = tid * 16;                                                            \
    int l = o ^ (((o >> 7) & 7) << 4);                                           \
    gld_lds16(kh + (size_t)(t) * 8192 + l, sK[b] + o);                           \
    gld_lds16(vh + (size_t)(o >> 7) * 4096 + (t) * 128 + (l & 127), sV[b] + o);  \
  }

  STAGE(0, 0);
  __builtin_amdgcn_sched_barrier(0);
  STAGE(1, 1);
  __builtin_amdgcn_sched_barrier(0);

  float l_run = 0.f;
  f32x16 oa0 = {}, oa1 = {};   // D[d][q]: d 0-31, d 32-63
  int cur = 0;

  for (int it = 0; it < 32; ++it) {
    if (it == 0 || it == 31) asm volatile("s_waitcnt vmcnt(0)" ::: "memory");
    else                     asm volatile("s_waitcnt vmcnt(2)" ::: "memory");
    __builtin_amdgcn_sched_barrier(0);
    __builtin_amdgcn_s_barrier();
    __builtin_amdgcn_sched_barrier(0);

    if (it + 2 < 32) {
      int sb = cur + 2; if (sb >= 3) sb -= 3;
      STAGE(it + 2, sb);
    }
    __builtin_amdgcn_sched_barrier(0);

    f32x16 sc0 = {}, sc1 = {};
    __builtin_amdgcn_s_setprio(1);
#pragma unroll
    for (int t = 0; t < 4; ++t) {
      int cx = (t * 32 + hi * 16) ^ swz;
      s16x8 k0 = *(const s16x8*)(sK[cur] + ql * 128 + cx);
      s16x8 k1 = *(const s16x8*)(sK[cur] + (32 + ql) * 128 + cx);
      sc0 = __builtin_amdgcn_mfma_f32_32x32x16_bf16(k0, qf[t], sc0, 0, 0, 0);
      sc1 = __builtin_amdgcn_mfma_f32_32x32x16_bf16(k1, qf[t], sc1, 0, 0, 0);
    }
    __builtin_amdgcn_s_setprio(0);

    float rs = 0.f;
#pragma unroll
    for (int r = 0; r < 16; ++r) { sc0[r] = __builtin_amdgcn_exp2f(sc0[r]); rs += sc0[r]; }
#pragma unroll
    for (int r = 0; r < 16; ++r) { sc1[r] = __builtin_amdgcn_exp2f(sc1[r]); rs += sc1[r]; }
    l_run += rs;

    unsigned int bp[16];
#pragma unroll
    for (int blk = 0; blk < 2; ++blk) {
      const f32x16& s = blk ? sc1 : sc0;
      unsigned int a0 = cvt_pk_bf16(s[0],  s[1]);
      unsigned int a1 = cvt_pk_bf16(s[2],  s[3]);
      unsigned int a2 = cvt_pk_bf16(s[4],  s[5]);
      unsigned int a3 = cvt_pk_bf16(s[6],  s[7]);
      pswap(a0, a2); pswap(a1, a3);
      bp[blk * 8 + 0] = a0; bp[blk * 8 + 1] = a1;
      bp[blk * 8 + 2] = a2; bp[blk * 8 + 3] = a3;
      unsigned int b0 = cvt_pk_bf16(s[8],  s[9]);
      unsigned int b1 = cvt_pk_bf16(s[10], s[11]);
      unsigned int b2 = cvt_pk_bf16(s[12], s[13]);
      unsigned int b3 = cvt_pk_bf16(s[14], s[15]);
      pswap(b0, b2); pswap(b1, b3);
      bp[blk * 8 + 4] = b0; bp[blk * 8 + 5] = b1;
      bp[blk * 8 + 6] = b2; bp[blk * 8 + 7] = b3;
    }

    __builtin_amdgcn_s_setprio(1);
#pragma unroll
    for (int ss = 0; ss < 4; ++ss) {
      uint4 u = {bp[ss * 4], bp[ss * 4 + 1], bp[ss * 4 + 2], bp[ss * 4 + 3]};
      s16x8 pb = __builtin_bit_cast(s16x8, u);
      int cx = (ss * 32 + hi * 16) ^ swz;
      s16x8 v0 = *(const s16x8*)(sV[cur] + ql * 128 + cx);
      s16x8 v1 = *(const s16x8*)(sV[cur] + (32 + ql) * 128 + cx);
      oa0 = __builtin_amdgcn_mfma_f32_32x32x16_bf16(v0, pb, oa0, 0, 0, 0);
      oa1 = __builtin_amdgcn_mfma_f32_32x32x16_bf16(v1, pb, oa1, 0, 0, 0);
    }
    __builtin_amdgcn_s_setprio(0);

    ++cur; if (cur == 3) cur = 0;
  }
#undef STAGE

  l_run += __shfl_xor(l_run, 32);
  float inv = 1.f / l_run;
  const int b = bh >> 4, h = bh & 15;
  const int q = q0 + 32 * w + ql;
  unsigned short* crow = Ctx + ((size_t)(b * 2048 + q)) * 1024 + h * 64;
#pragma unroll
  for (int dblk = 0; dblk < 2; ++dblk) {
    const f32x16& oa = dblk ? oa1 : oa0;
#pragma unroll
    for (int grp = 0; grp < 4; ++grp) {
      ushort4 st;
      st.x = f2bf(oa[4 * grp + 0] * inv);
      st.y = f2bf(oa[4 * grp + 1] * inv);
      st.z = f2bf(oa[4 * grp + 2] * inv);
      st.w = f2bf(oa[4 * grp + 3] * inv);
      *(ushort4*)(crow + dblk * 32 + 8 * grp + 4 * hi) = st;
    }
  }
}

extern "C" void kernel_launch(void* const* d_in, const int* in_sizes, int n_in,
                              void* d_out, int out_size, void* d_ws, size_t ws_size,
                              hipStream_t stream) {
  const float* hidden = (const float*)d_in[0];   // (4,2048,1024) f32
  const int*   pos    = (const int*)d_in[1];     // (4,2048) i32
  const float* wqkv   = (const float*)d_in[2];   // (3072,1024) f32
  const float* wo     = (const float*)d_in[3];   // (1024,1024) f32

  char* ws = (char*)d_ws;
  unsigned short* hbf  = (unsigned short*)(ws);                 // 16,777,216 B
  unsigned short* wqbf = (unsigned short*)(ws + 16777216);      //  6,291,456
  unsigned short* wobf = (unsigned short*)(ws + 23068672);      //  2,097,152
  unsigned short* Qr   = (unsigned short*)(ws + 41943040);      // 16,777,216
  unsigned short* Kr   = (unsigned short*)(ws + 58720256);      // 16,777,216
  unsigned short* Vt   = (unsigned short*)(ws + 75497472);      // 16,777,216
  unsigned short* ctx  = (unsigned short*)(ws + 92274688);      // 16,777,216
  float*          ctab = (float*)(ws + 109051904);              //  1,048,576
  float*          stab = (float*)(ws + 110100480);              //  1,048,576
  // total: 111,149,056 B

  cvt_rope_kernel<<<13312, 256, 0, stream>>>(hidden, wqkv, wo, pos,
                                             hbf, wqbf, wobf, ctab, stab);

  dim3 gq(32, 48);
  gemm3_kernel<2><<<gq, 256, 81920, stream>>>(hbf, wqbf, nullptr, 3072, 1024,
                                              ctab, stab, Qr, Kr, Vt);

  dim3 ga(8, 64);
  attn_kernel<<<ga, 512, 0, stream>>>(Qr, Kr, Vt, ctx);

  dim3 go(32, 16);
  gemm3_kernel<1><<<go, 256, 81920, stream>>>(ctx, wobf, d_out, 1024, 1024,
                                              nullptr, nullptr, nullptr, nullptr, nullptr);
}